// Round 3
// baseline (3753.066 us; speedup 1.0000x reference)
//
#include <hip/hip_runtime.h>
#include <math.h>

#define BB 8
#define NN 2048
#define PP 64
#define KK 32
#define DD 384
#define DEPTH 12
#define DI 768
#define DS 16
#define DCONV 4
#define DTR 24
#define NC 40
#define LL 128  // 2*PP
#define XROW (DTR + 2 * DS)  // 56
#define NR (BB * LL)         // 1024

// ---------------------------------------------------------------- helpers
__device__ __forceinline__ float gelu_exact(float x) {
    return 0.5f * x * (1.0f + erff(x * 0.70710678118654752440f));
}
__device__ __forceinline__ float siluf(float x) {
    return x / (1.0f + expf(-x));
}
__device__ __forceinline__ unsigned spread_bits(unsigned v) {
    v &= 1023u;
    v = (v | (v << 16)) & 50331903u;
    v = (v | (v << 8)) & 50393103u;
    v = (v | (v << 4)) & 51130563u;
    v = (v | (v << 2)) & 153391689u;
    return v;
}

// ---------------------------------------------------------------- KNN: one block per (b,p)
// d2+idx packed u64 kept in registers (8/thread); 32 rounds of min-reduce.
__global__ __launch_bounds__(256) void k_knn(const float* __restrict__ data,
                                             int* __restrict__ knn_out,
                                             float* __restrict__ centers)
{
    const int bp = blockIdx.x;
    const int b = bp >> 6, p = bp & 63;
    const int tid = threadIdx.x;
    const int lane = tid & 63, wid = tid >> 6;
    const float* X = data + (size_t)b * NN * 3;

    const float cx = X[p * 32 * 3 + 0];
    const float cy = X[p * 32 * 3 + 1];
    const float cz = X[p * 32 * 3 + 2];
    if (tid == 0) {
        centers[(b * PP + p) * 3 + 0] = cx;
        centers[(b * PP + p) * 3 + 1] = cy;
        centers[(b * PP + p) * 3 + 2] = cz;
    }

    unsigned long long pk[8];
#pragma unroll
    for (int q = 0; q < 8; q++) {
        int i = tid + 256 * q;
        float dx = cx - X[i * 3 + 0];
        float dy = cy - X[i * 3 + 1];
        float dz = cz - X[i * 3 + 2];
        float d2 = dx * dx + dy * dy + dz * dz;
        // d2 >= 0 -> float bits order-preserving as unsigned
        pk[q] = ((unsigned long long)__float_as_uint(d2) << 32) | (unsigned)i;
    }

    __shared__ unsigned long long wred[4];
    __shared__ int klist[KK];
    for (int k = 0; k < KK; k++) {
        unsigned long long m = pk[0];
#pragma unroll
        for (int q = 1; q < 8; q++) m = pk[q] < m ? pk[q] : m;
#pragma unroll
        for (int off = 32; off; off >>= 1) {
            unsigned long long o = __shfl_xor(m, off);
            m = o < m ? o : m;
        }
        if (lane == 0) wred[wid] = m;
        __syncthreads();
        unsigned long long g = wred[0];
#pragma unroll
        for (int w = 1; w < 4; w++) g = wred[w] < g ? wred[w] : g;
#pragma unroll
        for (int q = 0; q < 8; q++)
            if (pk[q] == g) pk[q] = ~0ull;   // unique idx -> exactly one owner
        if (tid == 0) klist[k] = (int)(g & 0xffffffffu);
        __syncthreads();
    }
    if (tid < KK) knn_out[bp * KK + tid] = klist[tid];
}

// ---------------------------------------------------------------- patch-embed MLP: one block per (b,p)
// 3->64->128->384 over 32 neighbors; layer3 register-blocked 6ch x 8nb per thread.
__global__ __launch_bounds__(256) void k_pe_mlp(
    const float* __restrict__ data, const int* __restrict__ knn_in,
    const float* __restrict__ w1, const float* __restrict__ b1,
    const float* __restrict__ g1, const float* __restrict__ be1,
    const float* __restrict__ w2, const float* __restrict__ b2,
    const float* __restrict__ g2, const float* __restrict__ be2,
    const float* __restrict__ w3, const float* __restrict__ b3,
    const float* __restrict__ g3, const float* __restrict__ be3,
    float* __restrict__ tokens)
{
    const int bp = blockIdx.x;
    const int b = bp >> 6, p = bp & 63;
    const int tid = threadIdx.x;
    const float* X = data + (size_t)b * NN * 3;
    const float inv_den = 0.99999500003749968752f; // 1/sqrt(1+1e-5)

    __shared__ float nxs[KK * 3];
    __shared__ float h1s[KK * 64];
    __shared__ float h2s[KK * 136];  // pad 136: 16B-aligned rows; jg lanes hit distinct banks

    const float cx = X[p * 32 * 3 + 0];
    const float cy = X[p * 32 * 3 + 1];
    const float cz = X[p * 32 * 3 + 2];
    if (tid < KK) {
        int q = knn_in[bp * KK + tid];
        nxs[tid * 3 + 0] = X[q * 3 + 0] - cx;
        nxs[tid * 3 + 1] = X[q * 3 + 1] - cy;
        nxs[tid * 3 + 2] = X[q * 3 + 2] - cz;
    }
    __syncthreads();

    for (int e = tid; e < KK * 64; e += 256) {
        int j = e >> 6, c = e & 63;
        float v = nxs[j * 3 + 0] * w1[c * 3 + 0] + nxs[j * 3 + 1] * w1[c * 3 + 1] +
                  nxs[j * 3 + 2] * w1[c * 3 + 2] + b1[c];
        v = v * (g1[c] * inv_den) + be1[c];
        h1s[j * 64 + c] = gelu_exact(v);
    }
    __syncthreads();

    for (int e = tid; e < KK * 128; e += 256) {
        int j = e >> 7, c = e & 127;
        const float4* wr = (const float4*)(w2 + (size_t)c * 64);
        const float4* hr = (const float4*)(h1s + j * 64);
        float acc = 0.f;
#pragma unroll
        for (int q = 0; q < 16; q++) {
            float4 wv = wr[q], hv = hr[q];
            acc += hv.x * wv.x + hv.y * wv.y + hv.z * wv.z + hv.w * wv.w;
        }
        float v = (acc + b2[c]) * (g2[c] * inv_den) + be2[c];
        h2s[j * 136 + c] = gelu_exact(v);
    }
    __syncthreads();

    // layer 3: thread = (cg, jg); channels c0..c0+5, neighbors j = jg + 4*jj
    const int cg = tid >> 2;     // 0..63
    const int jg = tid & 3;
    const int c0 = cg * 6;
    float acc[6][8];
#pragma unroll
    for (int i = 0; i < 6; i++)
#pragma unroll
        for (int j = 0; j < 8; j++) acc[i][j] = 0.f;

    for (int q = 0; q < 32; q++) {
        float4 hv[8];
#pragma unroll
        for (int jj = 0; jj < 8; jj++)
            hv[jj] = *(const float4*)(h2s + (jg + 4 * jj) * 136 + q * 4);
#pragma unroll
        for (int ci = 0; ci < 6; ci++) {
            float4 wv = *(const float4*)(w3 + (size_t)(c0 + ci) * 128 + q * 4);
#pragma unroll
            for (int jj = 0; jj < 8; jj++) {
                acc[ci][jj] += hv[jj].x * wv.x + hv[jj].y * wv.y +
                               hv[jj].z * wv.z + hv[jj].w * wv.w;
            }
        }
    }
#pragma unroll
    for (int ci = 0; ci < 6; ci++) {
        int c = c0 + ci;
        float bi = b3[c], sc = g3[c] * inv_den, sh = be3[c];
        float m = -3.4e38f;
#pragma unroll
        for (int jj = 0; jj < 8; jj++)
            m = fmaxf(m, (acc[ci][jj] + bi) * sc + sh);
        m = fmaxf(m, __shfl_xor(m, 1, 4));
        m = fmaxf(m, __shfl_xor(m, 2, 4));
        if (jg == 0) tokens[((size_t)b * PP + p) * DD + c] = m;
    }
}

// ---------------------------------------------------------------- SFC orders
__global__ __launch_bounds__(64) void k_sfc(const float* __restrict__ centers,
                                            int* __restrict__ order_h,
                                            int* __restrict__ order_th)
{
    const int b = blockIdx.x;
    const int tid = threadIdx.x; // 0..63
    float cc[3];
    cc[0] = centers[(b * PP + tid) * 3 + 0];
    cc[1] = centers[(b * PP + tid) * 3 + 1];
    cc[2] = centers[(b * PP + tid) * 3 + 2];

    __shared__ float csh[PP][3];
    __shared__ float slo[3], shi[3];
    csh[tid][0] = cc[0]; csh[tid][1] = cc[1]; csh[tid][2] = cc[2];
    __syncthreads();
    if (tid == 0) {
        for (int k = 0; k < 3; k++) {
            float lo = csh[0][k], hi = csh[0][k];
            for (int j = 1; j < PP; j++) { lo = fminf(lo, csh[j][k]); hi = fmaxf(hi, csh[j][k]); }
            slo[k] = lo; shi[k] = hi;
        }
    }
    __syncthreads();

    int q[3];
    for (int k = 0; k < 3; k++) {
        float t = (cc[k] - slo[k]) / (shi[k] - slo[k] + 1e-6f) * 1023.0f;
        int qi = (int)t;
        qi = qi < 0 ? 0 : (qi > 1023 ? 1023 : qi);
        q[k] = qi;
    }
    unsigned kh = spread_bits((unsigned)q[0]) | (spread_bits((unsigned)q[1]) << 1) |
                  (spread_bits((unsigned)q[2]) << 2);
    unsigned kt = spread_bits((unsigned)q[2]) | (spread_bits((unsigned)q[1]) << 1) |
                  (spread_bits((unsigned)q[0]) << 2);

    __shared__ unsigned khs[PP], kts[PP];
    khs[tid] = kh; kts[tid] = kt;
    __syncthreads();
    int rh = 0, rt = 0;
    for (int j = 0; j < PP; j++) {
        unsigned a = khs[j];
        rh += (a < kh) || (a == kh && j < tid);
        unsigned c = kts[j];
        rt += (c < kt) || (c == kt && j < tid);
    }
    order_h[b * PP + rh] = tid;
    order_th[b * PP + rt] = tid;
}

// ---------------------------------------------------------------- build token sequence
__global__ void k_build_t(const float* __restrict__ tokens,
                          const int* __restrict__ order_h, const int* __restrict__ order_th,
                          const float* __restrict__ hs, const float* __restrict__ hb,
                          const float* __restrict__ ts, const float* __restrict__ tb,
                          const float* __restrict__ pos, float* __restrict__ t)
{
    int idx = blockIdx.x * blockDim.x + threadIdx.x;
    if (idx >= BB * LL * DD) return;
    int d = idx % DD;
    int l = (idx / DD) % LL;
    int b = idx / (DD * LL);
    float v;
    if (l < PP) {
        int src = order_h[b * PP + l];
        v = tokens[((size_t)b * PP + src) * DD + d] * hs[d] + hb[d] + pos[l * DD + d];
    } else {
        int ll2 = l - PP;
        int src = order_th[b * PP + ll2];
        v = tokens[((size_t)b * PP + src) * DD + d] * ts[d] + tb[d] + pos[ll2 * DD + d];
    }
    t[idx] = v;
}

// ---------------------------------------------------------------- per-row LN stats (+ zero xdbl)
__global__ __launch_bounds__(256) void k_stats(const float* __restrict__ t,
                                               float* __restrict__ rmean,
                                               float* __restrict__ rinv,
                                               float* __restrict__ xdbl0)
{
    const int tid = threadIdx.x;
    const int wid = tid >> 6, lane = tid & 63;
    const int row = blockIdx.x * 4 + wid;   // grid = 256 -> rows 0..1023
    const float* xr = t + (size_t)row * DD;
    float v[6];
    float s = 0.f;
#pragma unroll
    for (int j = 0; j < 6; j++) { v[j] = xr[lane + 64 * j]; s += v[j]; }
#pragma unroll
    for (int off = 32; off; off >>= 1) s += __shfl_xor(s, off);
    float mean = s * (1.0f / DD);
    float vs = 0.f;
#pragma unroll
    for (int j = 0; j < 6; j++) { float dd = v[j] - mean; vs += dd * dd; }
#pragma unroll
    for (int off = 32; off; off >>= 1) vs += __shfl_xor(vs, off);
    float inv = 1.0f / sqrtf(vs * (1.0f / DD) + 1e-5f);
    if (lane == 0) { rmean[row] = mean; rinv[row] = inv; }

    int idx = blockIdx.x * 256 + tid;
    if (idx < NR * XROW) xdbl0[idx] = 0.f;
}

// ---------------------------------------------------------------- 64x128-tile fp32 GEMM, micro 4x8
// C[M,N] = A[M,K] * B[N,K]^T. Requires M%64==0, N%128==0, kchunk%16==0 (no bounds checks).
// NORM: apply ((a - mean[row]) * inv[row]) * g[k] + gb[k] to A during staging.
// MODE: 0 = store, 1 = atomicAdd.
template <int NORM, int MODE>
__global__ __launch_bounds__(256) void k_gemm128(
    const float* __restrict__ A, int lda,
    const float* __restrict__ B, int ldb,
    const float* __restrict__ rmean, const float* __restrict__ rinv,
    const float* __restrict__ g, const float* __restrict__ gb,
    float* __restrict__ C, int ldc,
    int kchunk)
{
    __shared__ float As[16][68];
    __shared__ float Bs[16][136];
    const int tid = threadIdx.x;
    const int tx = tid & 15;   // col group: cols tx*8 .. +7
    const int ty = tid >> 4;   // row group: rows ty*4 .. +3
    const int m0 = blockIdx.y * 64, n0 = blockIdx.x * 128;
    const int kbeg = blockIdx.z * kchunk;
    const int kend = kbeg + kchunk;

    const int lm = tid >> 2;          // 0..63
    const int lk = (tid & 3) * 4;     // 0,4,8,12

    const float* Arow  = A + (size_t)(m0 + lm) * lda;
    const float* Brow0 = B + (size_t)(n0 + lm) * ldb;
    const float* Brow1 = B + (size_t)(n0 + 64 + lm) * ldb;
    float mea = 0.f, inv = 0.f;
    if (NORM) { mea = rmean[m0 + lm]; inv = rinv[m0 + lm]; }

    float acc[4][8];
#pragma unroll
    for (int i = 0; i < 4; i++)
#pragma unroll
        for (int j = 0; j < 8; j++) acc[i][j] = 0.f;

    for (int k0 = kbeg; k0 < kend; k0 += 16) {
        int ak = k0 + lk;
        float4 av = *(const float4*)(Arow + ak);
        if (NORM) {
            float4 gv = *(const float4*)(g + ak);
            float4 bv = *(const float4*)(gb + ak);
            av.x = (av.x - mea) * inv * gv.x + bv.x;
            av.y = (av.y - mea) * inv * gv.y + bv.y;
            av.z = (av.z - mea) * inv * gv.z + bv.z;
            av.w = (av.w - mea) * inv * gv.w + bv.w;
        }
        float4 b0 = *(const float4*)(Brow0 + ak);
        float4 b1 = *(const float4*)(Brow1 + ak);
        As[lk + 0][lm] = av.x; As[lk + 1][lm] = av.y; As[lk + 2][lm] = av.z; As[lk + 3][lm] = av.w;
        Bs[lk + 0][lm] = b0.x; Bs[lk + 1][lm] = b0.y; Bs[lk + 2][lm] = b0.z; Bs[lk + 3][lm] = b0.w;
        Bs[lk + 0][64 + lm] = b1.x; Bs[lk + 1][64 + lm] = b1.y;
        Bs[lk + 2][64 + lm] = b1.z; Bs[lk + 3][64 + lm] = b1.w;
        __syncthreads();
#pragma unroll
        for (int kk = 0; kk < 16; kk++) {
            float4 a  = *(const float4*)(&As[kk][ty * 4]);
            float4 bA = *(const float4*)(&Bs[kk][tx * 8]);
            float4 bB = *(const float4*)(&Bs[kk][tx * 8 + 4]);
            acc[0][0] += a.x * bA.x; acc[0][1] += a.x * bA.y; acc[0][2] += a.x * bA.z; acc[0][3] += a.x * bA.w;
            acc[0][4] += a.x * bB.x; acc[0][5] += a.x * bB.y; acc[0][6] += a.x * bB.z; acc[0][7] += a.x * bB.w;
            acc[1][0] += a.y * bA.x; acc[1][1] += a.y * bA.y; acc[1][2] += a.y * bA.z; acc[1][3] += a.y * bA.w;
            acc[1][4] += a.y * bB.x; acc[1][5] += a.y * bB.y; acc[1][6] += a.y * bB.z; acc[1][7] += a.y * bB.w;
            acc[2][0] += a.z * bA.x; acc[2][1] += a.z * bA.y; acc[2][2] += a.z * bA.z; acc[2][3] += a.z * bA.w;
            acc[2][4] += a.z * bB.x; acc[2][5] += a.z * bB.y; acc[2][6] += a.z * bB.z; acc[2][7] += a.z * bB.w;
            acc[3][0] += a.w * bA.x; acc[3][1] += a.w * bA.y; acc[3][2] += a.w * bA.z; acc[3][3] += a.w * bA.w;
            acc[3][4] += a.w * bB.x; acc[3][5] += a.w * bB.y; acc[3][6] += a.w * bB.z; acc[3][7] += a.w * bB.w;
        }
        __syncthreads();
    }

    const int crow = m0 + ty * 4;
    const int ccol = n0 + tx * 8;
#pragma unroll
    for (int i = 0; i < 4; i++) {
        float* cp = C + (size_t)(crow + i) * ldc + ccol;
        if (MODE == 0) {
            *(float4*)cp       = make_float4(acc[i][0], acc[i][1], acc[i][2], acc[i][3]);
            *(float4*)(cp + 4) = make_float4(acc[i][4], acc[i][5], acc[i][6], acc[i][7]);
        } else {
#pragma unroll
            for (int j = 0; j < 8; j++) atomicAdd(&cp[j], acc[i][j]);
        }
    }
}

// ---------------------------------------------------------------- 64x64-tile GEMM (bounds-checked) for xdbl
template <int MODE>
__global__ __launch_bounds__(256) void k_gemm64(
    const float* __restrict__ A, int lda,
    const float* __restrict__ B, int ldb,
    float* __restrict__ C, int ldc,
    int M, int N, int K, int kchunk)
{
    __shared__ float As[16][68];
    __shared__ float Bs[16][68];
    const int tid = threadIdx.x;
    const int tx = tid & 15, ty = tid >> 4;
    const int m0 = blockIdx.y * 64, n0 = blockIdx.x * 64;
    const int kbeg = blockIdx.z * kchunk;
    const int kend = (kbeg + kchunk < K) ? (kbeg + kchunk) : K;

    const int lm = tid >> 2;
    const int lk = (tid & 3) * 4;

    float acc[4][4] = {};

    for (int k0 = kbeg; k0 < kend; k0 += 16) {
        float4 av = make_float4(0.f, 0.f, 0.f, 0.f);
        float4 bv = make_float4(0.f, 0.f, 0.f, 0.f);
        int ak = k0 + lk;
        int arow = m0 + lm, brow = n0 + lm;
        if (arow < M && ak + 3 < kend) av = *(const float4*)(A + (size_t)arow * lda + ak);
        if (brow < N && ak + 3 < kend) bv = *(const float4*)(B + (size_t)brow * ldb + ak);
        As[lk + 0][lm] = av.x; As[lk + 1][lm] = av.y; As[lk + 2][lm] = av.z; As[lk + 3][lm] = av.w;
        Bs[lk + 0][lm] = bv.x; Bs[lk + 1][lm] = bv.y; Bs[lk + 2][lm] = bv.z; Bs[lk + 3][lm] = bv.w;
        __syncthreads();
#pragma unroll
        for (int kk = 0; kk < 16; kk++) {
            float4 a = *(const float4*)(&As[kk][ty * 4]);
            float4 b = *(const float4*)(&Bs[kk][tx * 4]);
            acc[0][0] += a.x * b.x; acc[0][1] += a.x * b.y; acc[0][2] += a.x * b.z; acc[0][3] += a.x * b.w;
            acc[1][0] += a.y * b.x; acc[1][1] += a.y * b.y; acc[1][2] += a.y * b.z; acc[1][3] += a.y * b.w;
            acc[2][0] += a.z * b.x; acc[2][1] += a.z * b.y; acc[2][2] += a.z * b.z; acc[2][3] += a.z * b.w;
            acc[3][0] += a.w * b.x; acc[3][1] += a.w * b.y; acc[3][2] += a.w * b.z; acc[3][3] += a.w * b.w;
        }
        __syncthreads();
    }

    const int crow = m0 + ty * 4;
    const int ccol = n0 + tx * 4;
#pragma unroll
    for (int i = 0; i < 4; i++) {
        int r = crow + i;
        if (r >= M) continue;
        float* cp = C + (size_t)r * ldc + ccol;
#pragma unroll
        for (int j = 0; j < 4; j++) {
            if (ccol + j < N) {
                if (MODE == 0) cp[j] = acc[i][j];
                else atomicAdd(&cp[j], acc[i][j]);
            }
        }
    }
}

// ---------------------------------------------------------------- causal depthwise conv + silu
__global__ void k_conv(const float* __restrict__ xz, const float* __restrict__ cw,
                       const float* __restrict__ cb, float* __restrict__ xc)
{
    int idx = blockIdx.x * blockDim.x + threadIdx.x;
    if (idx >= BB * LL * DI) return;
    int c = idx % DI;
    int l = (idx / DI) % LL;
    int b = idx / (DI * LL);
    float acc = cb[c];
#pragma unroll
    for (int j = 0; j < DCONV; j++) {
        int lt = l - (DCONV - 1) + j;
        if (lt >= 0) acc += xz[((size_t)(b * LL + lt)) * (2 * DI) + c] * cw[c * DCONV + j];
    }
    xc[idx] = siluf(acc);
}

// ---------------------------------------------------------------- selective scan, delta-GEMM fused.
// 16 lanes per (b,d) channel; lane s owns state s.
__global__ __launch_bounds__(256) void k_scan(
    const float* __restrict__ xdbl, const float* __restrict__ xc,
    const float* __restrict__ xz,
    const float* __restrict__ dtw, const float* __restrict__ dtb,
    const float* __restrict__ Alog, const float* __restrict__ Dp,
    float* __restrict__ y)
{
    const int tid = threadIdx.x;
    const int s = tid & 15;
    const int ch = blockIdx.x * 16 + (tid >> 4);  // 0..6143
    const int b = ch / DI, d = ch % DI;
    const float As_ = -__expf(Alog[d * DS + s]);
    const float Dd = Dp[d];
    const float dw0 = dtw[d * DTR + s];
    const float dw1 = (s < 8) ? dtw[d * DTR + 16 + s] : 0.f;
    const float db_ = dtb[d];
    float h = 0.f;
    for (int t = 0; t < LL; t++) {
        size_t row = (size_t)b * LL + t;
        const float* xd = xdbl + row * XROW;
        float u = xc[row * DI + d];
        float dp = xd[s] * dw0;
        if (s < 8) dp += xd[16 + s] * dw1;
        dp += __shfl_xor(dp, 1, 16);
        dp += __shfl_xor(dp, 2, 16);
        dp += __shfl_xor(dp, 4, 16);
        dp += __shfl_xor(dp, 8, 16);
        float vraw = dp + db_;
        float delta = fmaxf(vraw, 0.f) + log1pf(__expf(-fabsf(vraw)));  // softplus
        float Bv = xd[DTR + s];
        float Cv = xd[DTR + DS + s];
        h = h * __expf(delta * As_) + delta * u * Bv;
        float p = h * Cv;
        p += __shfl_xor(p, 1, 16);
        p += __shfl_xor(p, 2, 16);
        p += __shfl_xor(p, 4, 16);
        p += __shfl_xor(p, 8, 16);
        if (s == 0) {
            float z = xz[row * (2 * DI) + DI + d];
            y[row * DI + d] = (p + Dd * u) * siluf(z);
        }
    }
}

// ---------------------------------------------------------------- final layernorm (wave per row)
__global__ __launch_bounds__(64) void k_ln(const float* __restrict__ x,
                                           const float* __restrict__ g,
                                           const float* __restrict__ bb,
                                           float* __restrict__ y)
{
    const int row = blockIdx.x;
    const int tid = threadIdx.x;
    const float* xr = x + (size_t)row * DD;
    float v[6];
    float s = 0.f;
#pragma unroll
    for (int j = 0; j < 6; j++) { v[j] = xr[tid + 64 * j]; s += v[j]; }
#pragma unroll
    for (int off = 32; off; off >>= 1) s += __shfl_xor(s, off);
    float mean = s * (1.0f / DD);
    float vs = 0.f;
#pragma unroll
    for (int j = 0; j < 6; j++) { float dd = v[j] - mean; vs += dd * dd; }
#pragma unroll
    for (int off = 32; off; off >>= 1) vs += __shfl_xor(vs, off);
    float inv = 1.0f / sqrtf(vs * (1.0f / DD) + 1e-5f);
#pragma unroll
    for (int j = 0; j < 6; j++) {
        int i = tid + 64 * j;
        y[(size_t)row * DD + i] = (v[j] - mean) * inv * g[i] + bb[i];
    }
}

// ---------------------------------------------------------------- mean over L
__global__ void k_mean(const float* __restrict__ xln, float* __restrict__ pooled)
{
    int idx = blockIdx.x * blockDim.x + threadIdx.x;
    if (idx >= BB * DD) return;
    int b = idx / DD, d = idx % DD;
    float sv = 0.f;
    for (int l = 0; l < LL; l++) sv += xln[((size_t)b * LL + l) * DD + d];
    pooled[idx] = sv / (float)LL;
}

// ---------------------------------------------------------------- head MLP (one block per batch)
__global__ __launch_bounds__(256) void k_mlp(const float* __restrict__ pooled,
    const float* __restrict__ w1, const float* __restrict__ b1,
    const float* __restrict__ w2, const float* __restrict__ b2,
    const float* __restrict__ w3, const float* __restrict__ b3,
    float* __restrict__ out)
{
    int b = blockIdx.x, tid = threadIdx.x;
    __shared__ float pl[DD];
    __shared__ float h1[256];
    __shared__ float h2[64];
    for (int i = tid; i < DD; i += 256) pl[i] = pooled[b * DD + i];
    __syncthreads();
    {
        float acc = b1[tid];
        const float* wr = w1 + (size_t)tid * DD;
        for (int k = 0; k < DD; k++) acc += pl[k] * wr[k];
        h1[tid] = fmaxf(acc, 0.f);
    }
    __syncthreads();
    if (tid < 64) {
        float acc = b2[tid];
        const float* wr = w2 + (size_t)tid * 256;
        for (int k = 0; k < 256; k++) acc += h1[k] * wr[k];
        h2[tid] = fmaxf(acc, 0.f);
    }
    __syncthreads();
    if (tid < NC) {
        float acc = b3[tid];
        const float* wr = w3 + (size_t)tid * 64;
        for (int k = 0; k < 64; k++) acc += h2[k] * wr[k];
        out[b * NC + tid] = acc;
    }
}

// ---------------------------------------------------------------- launch
extern "C" void kernel_launch(void* const* d_in, const int* in_sizes, int n_in,
                              void* d_out, int out_size, void* d_ws, size_t ws_size,
                              hipStream_t stream)
{
    const float* data      = (const float*)d_in[0];
    const float* pe_w1     = (const float*)d_in[1];
    const float* pe_b1     = (const float*)d_in[2];
    const float* pe_g1     = (const float*)d_in[3];
    const float* pe_be1    = (const float*)d_in[4];
    const float* pe_w2     = (const float*)d_in[5];
    const float* pe_b2     = (const float*)d_in[6];
    const float* pe_g2     = (const float*)d_in[7];
    const float* pe_be2    = (const float*)d_in[8];
    const float* pe_w3     = (const float*)d_in[9];
    const float* pe_b3     = (const float*)d_in[10];
    const float* pe_g3     = (const float*)d_in[11];
    const float* pe_be3    = (const float*)d_in[12];
    const float* oi_h_scale  = (const float*)d_in[13];
    const float* oi_h_shift  = (const float*)d_in[14];
    const float* oi_th_scale = (const float*)d_in[15];
    const float* oi_th_shift = (const float*)d_in[16];
    const float* pos_embed = (const float*)d_in[17];
    const float* blk_ln_g  = (const float*)d_in[18];
    const float* blk_ln_b  = (const float*)d_in[19];
    const float* blk_in_w  = (const float*)d_in[20];
    const float* blk_conv_w = (const float*)d_in[21];
    const float* blk_conv_b = (const float*)d_in[22];
    const float* blk_xp_w  = (const float*)d_in[23];
    const float* blk_dt_w  = (const float*)d_in[24];
    const float* blk_dt_b  = (const float*)d_in[25];
    const float* blk_Alog  = (const float*)d_in[26];
    const float* blk_D     = (const float*)d_in[27];
    const float* blk_out_w = (const float*)d_in[28];
    const float* norm_g    = (const float*)d_in[29];
    const float* norm_b    = (const float*)d_in[30];
    const float* mlp_w1    = (const float*)d_in[31];
    const float* mlp_b1    = (const float*)d_in[32];
    const float* mlp_w2    = (const float*)d_in[33];
    const float* mlp_b2    = (const float*)d_in[34];
    const float* mlp_w3    = (const float*)d_in[35];
    const float* mlp_b3    = (const float*)d_in[36];

    float* ws = (float*)d_ws;
    size_t off = 0;
    auto alloc = [&](size_t n) { float* p = ws + off; off += (n + 63) & ~(size_t)63; return p; };
    float* tokens  = alloc((size_t)BB * PP * DD);
    float* centers = alloc((size_t)BB * PP * 3);
    int*   order_h = (int*)alloc((size_t)BB * PP);
    int*   order_th= (int*)alloc((size_t)BB * PP);
    int*   knn_idx = (int*)alloc((size_t)BB * PP * KK);
    float* t    = alloc((size_t)NR * DD);
    float* xln  = alloc((size_t)NR * DD);
    float* xz   = alloc((size_t)NR * 2 * DI);
    float* xc   = alloc((size_t)NR * DI);
    float* xdbl = alloc((size_t)NR * XROW);
    float* yb   = alloc((size_t)NR * DI);
    float* rmean= alloc(NR);
    float* rinv = alloc(NR);
    float* pooled = alloc((size_t)BB * DD);

    k_knn<<<BB * PP, 256, 0, stream>>>(data, knn_idx, centers);
    k_pe_mlp<<<BB * PP, 256, 0, stream>>>(data, knn_idx,
        pe_w1, pe_b1, pe_g1, pe_be1, pe_w2, pe_b2, pe_g2, pe_be2,
        pe_w3, pe_b3, pe_g3, pe_be3, tokens);
    k_sfc<<<BB, 64, 0, stream>>>(centers, order_h, order_th);
    {
        int nt = BB * LL * DD;
        k_build_t<<<(nt + 255) / 256, 256, 0, stream>>>(tokens, order_h, order_th,
            oi_h_scale, oi_h_shift, oi_th_scale, oi_th_shift, pos_embed, t);
    }

    for (int i = 0; i < DEPTH; i++) {
        const float* ln_g = blk_ln_g + i * DD;
        const float* ln_b = blk_ln_b + i * DD;
        const float* in_w = blk_in_w + (size_t)i * 2 * DI * DD;
        const float* cw   = blk_conv_w + (size_t)i * DI * DCONV;
        const float* cb   = blk_conv_b + (size_t)i * DI;
        const float* xp   = blk_xp_w + (size_t)i * XROW * DI;
        const float* dtw  = blk_dt_w + (size_t)i * DI * DTR;
        const float* dtb  = blk_dt_b + (size_t)i * DI;
        const float* Al   = blk_Alog + (size_t)i * DI * DS;
        const float* Dpp  = blk_D + (size_t)i * DI;
        const float* ow   = blk_out_w + (size_t)i * DD * DI;

        // LN row stats + zero xdbl
        k_stats<<<NR / 4, 256, 0, stream>>>(t, rmean, rinv, xdbl);
        // xz = LN(t) @ in_w^T   (1024 x 1536, K=384), norm fused into A staging
        k_gemm128<1, 0><<<dim3(2 * DI / 128, NR / 64, 1), 256, 0, stream>>>(
            t, DD, in_w, DD, rmean, rinv, ln_g, ln_b, xz, 2 * DI, DD);
        k_conv<<<(NR * DI + 255) / 256, 256, 0, stream>>>(xz, cw, cb, xc);
        // xdbl = xc @ xp^T  (1024 x 56, K=768), split-K x4 atomic
        k_gemm64<1><<<dim3(1, NR / 64, 4), 256, 0, stream>>>(
            xc, DI, xp, DI, xdbl, XROW, NR, XROW, DI, DI / 4);
        // scan with fused delta = softplus(xdbl[:, :24] @ dt_w^T + dt_b)
        k_scan<<<(BB * DI) / 16, 256, 0, stream>>>(xdbl, xc, xz, dtw, dtb, Al, Dpp, yb);
        // t += yb @ out_w^T  (1024 x 384, K=768), split-K x4 atomic (residual accum)
        k_gemm128<0, 1><<<dim3(DD / 128, NR / 64, 4), 256, 0, stream>>>(
            yb, DI, ow, DI, nullptr, nullptr, nullptr, nullptr, t, DD, DI / 4);
    }

    k_ln<<<NR, 64, 0, stream>>>(t, norm_g, norm_b, xln);
    k_mean<<<(BB * DD + 255) / 256, 256, 0, stream>>>(xln, pooled);
    k_mlp<<<BB, 256, 0, stream>>>(pooled, mlp_w1, mlp_b1, mlp_w2, mlp_b2, mlp_w3, mlp_b3,
                                  (float*)d_out);
}

// Round 4
// 2267.688 us; speedup vs baseline: 1.6550x; 1.6550x over previous
//
#include <hip/hip_runtime.h>
#include <math.h>

#define BB 8
#define NN 2048
#define PP 64
#define KK 32
#define DD 384
#define DEPTH 12
#define DI 768
#define DS 16
#define DCONV 4
#define DTR 24
#define NC 40
#define LL 128  // 2*PP
#define XROW (DTR + 2 * DS)  // 56
#define NR (BB * LL)         // 1024

// ---------------------------------------------------------------- helpers
__device__ __forceinline__ float gelu_exact(float x) {
    return 0.5f * x * (1.0f + erff(x * 0.70710678118654752440f));
}
__device__ __forceinline__ float siluf(float x) {
    return x / (1.0f + expf(-x));
}
__device__ __forceinline__ unsigned spread_bits(unsigned v) {
    v &= 1023u;
    v = (v | (v << 16)) & 50331903u;
    v = (v | (v << 8)) & 50393103u;
    v = (v | (v << 4)) & 51130563u;
    v = (v | (v << 2)) & 153391689u;
    return v;
}

// ---------------------------------------------------------------- KNN: one block per (b,p)
__global__ __launch_bounds__(256) void k_knn(const float* __restrict__ data,
                                             int* __restrict__ knn_out,
                                             float* __restrict__ centers)
{
    const int bp = blockIdx.x;
    const int b = bp >> 6, p = bp & 63;
    const int tid = threadIdx.x;
    const int lane = tid & 63, wid = tid >> 6;
    const float* X = data + (size_t)b * NN * 3;

    const float cx = X[p * 32 * 3 + 0];
    const float cy = X[p * 32 * 3 + 1];
    const float cz = X[p * 32 * 3 + 2];
    if (tid == 0) {
        centers[(b * PP + p) * 3 + 0] = cx;
        centers[(b * PP + p) * 3 + 1] = cy;
        centers[(b * PP + p) * 3 + 2] = cz;
    }

    unsigned long long pk[8];
#pragma unroll
    for (int q = 0; q < 8; q++) {
        int i = tid + 256 * q;
        float dx = cx - X[i * 3 + 0];
        float dy = cy - X[i * 3 + 1];
        float dz = cz - X[i * 3 + 2];
        float d2 = dx * dx + dy * dy + dz * dz;
        pk[q] = ((unsigned long long)__float_as_uint(d2) << 32) | (unsigned)i;
    }

    __shared__ unsigned long long wred[4];
    __shared__ int klist[KK];
    for (int k = 0; k < KK; k++) {
        unsigned long long m = pk[0];
#pragma unroll
        for (int q = 1; q < 8; q++) m = pk[q] < m ? pk[q] : m;
#pragma unroll
        for (int off = 32; off; off >>= 1) {
            unsigned long long o = __shfl_xor(m, off);
            m = o < m ? o : m;
        }
        if (lane == 0) wred[wid] = m;
        __syncthreads();
        unsigned long long g = wred[0];
#pragma unroll
        for (int w = 1; w < 4; w++) g = wred[w] < g ? wred[w] : g;
#pragma unroll
        for (int q = 0; q < 8; q++)
            if (pk[q] == g) pk[q] = ~0ull;
        if (tid == 0) klist[k] = (int)(g & 0xffffffffu);
        __syncthreads();
    }
    if (tid < KK) knn_out[bp * KK + tid] = klist[tid];
}

// ---------------------------------------------------------------- patch-embed MLP: one block per (b,p)
__global__ __launch_bounds__(256) void k_pe_mlp(
    const float* __restrict__ data, const int* __restrict__ knn_in,
    const float* __restrict__ w1, const float* __restrict__ b1,
    const float* __restrict__ g1, const float* __restrict__ be1,
    const float* __restrict__ w2, const float* __restrict__ b2,
    const float* __restrict__ g2, const float* __restrict__ be2,
    const float* __restrict__ w3, const float* __restrict__ b3,
    const float* __restrict__ g3, const float* __restrict__ be3,
    float* __restrict__ tokens)
{
    const int bp = blockIdx.x;
    const int b = bp >> 6, p = bp & 63;
    const int tid = threadIdx.x;
    const float* X = data + (size_t)b * NN * 3;
    const float inv_den = 0.99999500003749968752f; // 1/sqrt(1+1e-5)

    __shared__ float nxs[KK * 3];
    __shared__ float h1s[KK * 64];
    __shared__ float h2s[KK * 136];

    const float cx = X[p * 32 * 3 + 0];
    const float cy = X[p * 32 * 3 + 1];
    const float cz = X[p * 32 * 3 + 2];
    if (tid < KK) {
        int q = knn_in[bp * KK + tid];
        nxs[tid * 3 + 0] = X[q * 3 + 0] - cx;
        nxs[tid * 3 + 1] = X[q * 3 + 1] - cy;
        nxs[tid * 3 + 2] = X[q * 3 + 2] - cz;
    }
    __syncthreads();

    for (int e = tid; e < KK * 64; e += 256) {
        int j = e >> 6, c = e & 63;
        float v = nxs[j * 3 + 0] * w1[c * 3 + 0] + nxs[j * 3 + 1] * w1[c * 3 + 1] +
                  nxs[j * 3 + 2] * w1[c * 3 + 2] + b1[c];
        v = v * (g1[c] * inv_den) + be1[c];
        h1s[j * 64 + c] = gelu_exact(v);
    }
    __syncthreads();

    for (int e = tid; e < KK * 128; e += 256) {
        int j = e >> 7, c = e & 127;
        const float4* wr = (const float4*)(w2 + (size_t)c * 64);
        const float4* hr = (const float4*)(h1s + j * 64);
        float acc = 0.f;
#pragma unroll
        for (int q = 0; q < 16; q++) {
            float4 wv = wr[q], hv = hr[q];
            acc += hv.x * wv.x + hv.y * wv.y + hv.z * wv.z + hv.w * wv.w;
        }
        float v = (acc + b2[c]) * (g2[c] * inv_den) + be2[c];
        h2s[j * 136 + c] = gelu_exact(v);
    }
    __syncthreads();

    const int cg = tid >> 2;
    const int jg = tid & 3;
    const int c0 = cg * 6;
    float acc[6][8];
#pragma unroll
    for (int i = 0; i < 6; i++)
#pragma unroll
        for (int j = 0; j < 8; j++) acc[i][j] = 0.f;

    for (int q = 0; q < 32; q++) {
        float4 hv[8];
#pragma unroll
        for (int jj = 0; jj < 8; jj++)
            hv[jj] = *(const float4*)(h2s + (jg + 4 * jj) * 136 + q * 4);
#pragma unroll
        for (int ci = 0; ci < 6; ci++) {
            float4 wv = *(const float4*)(w3 + (size_t)(c0 + ci) * 128 + q * 4);
#pragma unroll
            for (int jj = 0; jj < 8; jj++) {
                acc[ci][jj] += hv[jj].x * wv.x + hv[jj].y * wv.y +
                               hv[jj].z * wv.z + hv[jj].w * wv.w;
            }
        }
    }
#pragma unroll
    for (int ci = 0; ci < 6; ci++) {
        int c = c0 + ci;
        float bi = b3[c], sc = g3[c] * inv_den, sh = be3[c];
        float m = -3.4e38f;
#pragma unroll
        for (int jj = 0; jj < 8; jj++)
            m = fmaxf(m, (acc[ci][jj] + bi) * sc + sh);
        m = fmaxf(m, __shfl_xor(m, 1, 4));
        m = fmaxf(m, __shfl_xor(m, 2, 4));
        if (jg == 0) tokens[((size_t)b * PP + p) * DD + c] = m;
    }
}

// ---------------------------------------------------------------- SFC orders
__global__ __launch_bounds__(64) void k_sfc(const float* __restrict__ centers,
                                            int* __restrict__ order_h,
                                            int* __restrict__ order_th)
{
    const int b = blockIdx.x;
    const int tid = threadIdx.x;
    float cc[3];
    cc[0] = centers[(b * PP + tid) * 3 + 0];
    cc[1] = centers[(b * PP + tid) * 3 + 1];
    cc[2] = centers[(b * PP + tid) * 3 + 2];

    __shared__ float csh[PP][3];
    __shared__ float slo[3], shi[3];
    csh[tid][0] = cc[0]; csh[tid][1] = cc[1]; csh[tid][2] = cc[2];
    __syncthreads();
    if (tid == 0) {
        for (int k = 0; k < 3; k++) {
            float lo = csh[0][k], hi = csh[0][k];
            for (int j = 1; j < PP; j++) { lo = fminf(lo, csh[j][k]); hi = fmaxf(hi, csh[j][k]); }
            slo[k] = lo; shi[k] = hi;
        }
    }
    __syncthreads();

    int q[3];
    for (int k = 0; k < 3; k++) {
        float t = (cc[k] - slo[k]) / (shi[k] - slo[k] + 1e-6f) * 1023.0f;
        int qi = (int)t;
        qi = qi < 0 ? 0 : (qi > 1023 ? 1023 : qi);
        q[k] = qi;
    }
    unsigned kh = spread_bits((unsigned)q[0]) | (spread_bits((unsigned)q[1]) << 1) |
                  (spread_bits((unsigned)q[2]) << 2);
    unsigned kt = spread_bits((unsigned)q[2]) | (spread_bits((unsigned)q[1]) << 1) |
                  (spread_bits((unsigned)q[0]) << 2);

    __shared__ unsigned khs[PP], kts[PP];
    khs[tid] = kh; kts[tid] = kt;
    __syncthreads();
    int rh = 0, rt = 0;
    for (int j = 0; j < PP; j++) {
        unsigned a = khs[j];
        rh += (a < kh) || (a == kh && j < tid);
        unsigned c = kts[j];
        rt += (c < kt) || (c == kt && j < tid);
    }
    order_h[b * PP + rh] = tid;
    order_th[b * PP + rt] = tid;
}

// ---------------------------------------------------------------- build token sequence
__global__ void k_build_t(const float* __restrict__ tokens,
                          const int* __restrict__ order_h, const int* __restrict__ order_th,
                          const float* __restrict__ hs, const float* __restrict__ hb,
                          const float* __restrict__ ts, const float* __restrict__ tb,
                          const float* __restrict__ pos, float* __restrict__ t)
{
    int idx = blockIdx.x * blockDim.x + threadIdx.x;
    if (idx >= BB * LL * DD) return;
    int d = idx % DD;
    int l = (idx / DD) % LL;
    int b = idx / (DD * LL);
    float v;
    if (l < PP) {
        int src = order_h[b * PP + l];
        v = tokens[((size_t)b * PP + src) * DD + d] * hs[d] + hb[d] + pos[l * DD + d];
    } else {
        int ll2 = l - PP;
        int src = order_th[b * PP + ll2];
        v = tokens[((size_t)b * PP + src) * DD + d] * ts[d] + tb[d] + pos[ll2 * DD + d];
    }
    t[idx] = v;
}

// ---------------------------------------------------------------- per-row LN stats (+ zero xdbl)
__global__ __launch_bounds__(256) void k_stats(const float* __restrict__ t,
                                               float* __restrict__ rmean,
                                               float* __restrict__ rinv,
                                               float* __restrict__ xdbl0)
{
    const int tid = threadIdx.x;
    const int wid = tid >> 6, lane = tid & 63;
    const int row = blockIdx.x * 4 + wid;
    const float* xr = t + (size_t)row * DD;
    float v[6];
    float s = 0.f;
#pragma unroll
    for (int j = 0; j < 6; j++) { v[j] = xr[lane + 64 * j]; s += v[j]; }
#pragma unroll
    for (int off = 32; off; off >>= 1) s += __shfl_xor(s, off);
    float mean = s * (1.0f / DD);
    float vs = 0.f;
#pragma unroll
    for (int j = 0; j < 6; j++) { float dd = v[j] - mean; vs += dd * dd; }
#pragma unroll
    for (int off = 32; off; off >>= 1) vs += __shfl_xor(vs, off);
    float inv = 1.0f / sqrtf(vs * (1.0f / DD) + 1e-5f);
    if (lane == 0) { rmean[row] = mean; rinv[row] = inv; }

    int idx = blockIdx.x * 256 + tid;
    if (idx < NR * XROW) xdbl0[idx] = 0.f;
}

// ---------------------------------------------------------------- 64x128-tile fp32 GEMM, micro 4x8
template <int NORM, int MODE>
__global__ __launch_bounds__(256) void k_gemm128(
    const float* __restrict__ A, int lda,
    const float* __restrict__ B, int ldb,
    const float* __restrict__ rmean, const float* __restrict__ rinv,
    const float* __restrict__ g, const float* __restrict__ gb,
    float* __restrict__ C, int ldc,
    int kchunk)
{
    __shared__ float As[16][68];
    __shared__ float Bs[16][136];
    const int tid = threadIdx.x;
    const int tx = tid & 15;
    const int ty = tid >> 4;
    const int m0 = blockIdx.y * 64, n0 = blockIdx.x * 128;
    const int kbeg = blockIdx.z * kchunk;
    const int kend = kbeg + kchunk;

    const int lm = tid >> 2;
    const int lk = (tid & 3) * 4;

    const float* Arow  = A + (size_t)(m0 + lm) * lda;
    const float* Brow0 = B + (size_t)(n0 + lm) * ldb;
    const float* Brow1 = B + (size_t)(n0 + 64 + lm) * ldb;
    float mea = 0.f, inv = 0.f;
    if (NORM) { mea = rmean[m0 + lm]; inv = rinv[m0 + lm]; }

    float acc[4][8];
#pragma unroll
    for (int i = 0; i < 4; i++)
#pragma unroll
        for (int j = 0; j < 8; j++) acc[i][j] = 0.f;

    for (int k0 = kbeg; k0 < kend; k0 += 16) {
        int ak = k0 + lk;
        float4 av = *(const float4*)(Arow + ak);
        if (NORM) {
            float4 gv = *(const float4*)(g + ak);
            float4 bv = *(const float4*)(gb + ak);
            av.x = (av.x - mea) * inv * gv.x + bv.x;
            av.y = (av.y - mea) * inv * gv.y + bv.y;
            av.z = (av.z - mea) * inv * gv.z + bv.z;
            av.w = (av.w - mea) * inv * gv.w + bv.w;
        }
        float4 b0 = *(const float4*)(Brow0 + ak);
        float4 b1 = *(const float4*)(Brow1 + ak);
        As[lk + 0][lm] = av.x; As[lk + 1][lm] = av.y; As[lk + 2][lm] = av.z; As[lk + 3][lm] = av.w;
        Bs[lk + 0][lm] = b0.x; Bs[lk + 1][lm] = b0.y; Bs[lk + 2][lm] = b0.z; Bs[lk + 3][lm] = b0.w;
        Bs[lk + 0][64 + lm] = b1.x; Bs[lk + 1][64 + lm] = b1.y;
        Bs[lk + 2][64 + lm] = b1.z; Bs[lk + 3][64 + lm] = b1.w;
        __syncthreads();
#pragma unroll
        for (int kk = 0; kk < 16; kk++) {
            float4 a  = *(const float4*)(&As[kk][ty * 4]);
            float4 bA = *(const float4*)(&Bs[kk][tx * 8]);
            float4 bB = *(const float4*)(&Bs[kk][tx * 8 + 4]);
            acc[0][0] += a.x * bA.x; acc[0][1] += a.x * bA.y; acc[0][2] += a.x * bA.z; acc[0][3] += a.x * bA.w;
            acc[0][4] += a.x * bB.x; acc[0][5] += a.x * bB.y; acc[0][6] += a.x * bB.z; acc[0][7] += a.x * bB.w;
            acc[1][0] += a.y * bA.x; acc[1][1] += a.y * bA.y; acc[1][2] += a.y * bA.z; acc[1][3] += a.y * bA.w;
            acc[1][4] += a.y * bB.x; acc[1][5] += a.y * bB.y; acc[1][6] += a.y * bB.z; acc[1][7] += a.y * bB.w;
            acc[2][0] += a.z * bA.x; acc[2][1] += a.z * bA.y; acc[2][2] += a.z * bA.z; acc[2][3] += a.z * bA.w;
            acc[2][4] += a.z * bB.x; acc[2][5] += a.z * bB.y; acc[2][6] += a.z * bB.z; acc[2][7] += a.z * bB.w;
            acc[3][0] += a.w * bA.x; acc[3][1] += a.w * bA.y; acc[3][2] += a.w * bA.z; acc[3][3] += a.w * bA.w;
            acc[3][4] += a.w * bB.x; acc[3][5] += a.w * bB.y; acc[3][6] += a.w * bB.z; acc[3][7] += a.w * bB.w;
        }
        __syncthreads();
    }

    const int crow = m0 + ty * 4;
    const int ccol = n0 + tx * 8;
#pragma unroll
    for (int i = 0; i < 4; i++) {
        float* cp = C + (size_t)(crow + i) * ldc + ccol;
        if (MODE == 0) {
            *(float4*)cp       = make_float4(acc[i][0], acc[i][1], acc[i][2], acc[i][3]);
            *(float4*)(cp + 4) = make_float4(acc[i][4], acc[i][5], acc[i][6], acc[i][7]);
        } else {
#pragma unroll
            for (int j = 0; j < 8; j++) atomicAdd(&cp[j], acc[i][j]);
        }
    }
}

// ---------------------------------------------------------------- 64x64-tile GEMM (bounds-checked) for xdbl
template <int MODE>
__global__ __launch_bounds__(256) void k_gemm64(
    const float* __restrict__ A, int lda,
    const float* __restrict__ B, int ldb,
    float* __restrict__ C, int ldc,
    int M, int N, int K, int kchunk)
{
    __shared__ float As[16][68];
    __shared__ float Bs[16][68];
    const int tid = threadIdx.x;
    const int tx = tid & 15, ty = tid >> 4;
    const int m0 = blockIdx.y * 64, n0 = blockIdx.x * 64;
    const int kbeg = blockIdx.z * kchunk;
    const int kend = (kbeg + kchunk < K) ? (kbeg + kchunk) : K;

    const int lm = tid >> 2;
    const int lk = (tid & 3) * 4;

    float acc[4][4] = {};

    for (int k0 = kbeg; k0 < kend; k0 += 16) {
        float4 av = make_float4(0.f, 0.f, 0.f, 0.f);
        float4 bv = make_float4(0.f, 0.f, 0.f, 0.f);
        int ak = k0 + lk;
        int arow = m0 + lm, brow = n0 + lm;
        if (arow < M && ak + 3 < kend) av = *(const float4*)(A + (size_t)arow * lda + ak);
        if (brow < N && ak + 3 < kend) bv = *(const float4*)(B + (size_t)brow * ldb + ak);
        As[lk + 0][lm] = av.x; As[lk + 1][lm] = av.y; As[lk + 2][lm] = av.z; As[lk + 3][lm] = av.w;
        Bs[lk + 0][lm] = bv.x; Bs[lk + 1][lm] = bv.y; Bs[lk + 2][lm] = bv.z; Bs[lk + 3][lm] = bv.w;
        __syncthreads();
#pragma unroll
        for (int kk = 0; kk < 16; kk++) {
            float4 a = *(const float4*)(&As[kk][ty * 4]);
            float4 b = *(const float4*)(&Bs[kk][tx * 4]);
            acc[0][0] += a.x * b.x; acc[0][1] += a.x * b.y; acc[0][2] += a.x * b.z; acc[0][3] += a.x * b.w;
            acc[1][0] += a.y * b.x; acc[1][1] += a.y * b.y; acc[1][2] += a.y * b.z; acc[1][3] += a.y * b.w;
            acc[2][0] += a.z * b.x; acc[2][1] += a.z * b.y; acc[2][2] += a.z * b.z; acc[2][3] += a.z * b.w;
            acc[3][0] += a.w * b.x; acc[3][1] += a.w * b.y; acc[3][2] += a.w * b.z; acc[3][3] += a.w * b.w;
        }
        __syncthreads();
    }

    const int crow = m0 + ty * 4;
    const int ccol = n0 + tx * 4;
#pragma unroll
    for (int i = 0; i < 4; i++) {
        int r = crow + i;
        if (r >= M) continue;
        float* cp = C + (size_t)r * ldc + ccol;
#pragma unroll
        for (int j = 0; j < 4; j++) {
            if (ccol + j < N) {
                if (MODE == 0) cp[j] = acc[i][j];
                else atomicAdd(&cp[j], acc[i][j]);
            }
        }
    }
}

// ---------------------------------------------------------------- causal depthwise conv + silu
__global__ void k_conv(const float* __restrict__ xz, const float* __restrict__ cw,
                       const float* __restrict__ cb, float* __restrict__ xc)
{
    int idx = blockIdx.x * blockDim.x + threadIdx.x;
    if (idx >= BB * LL * DI) return;
    int c = idx % DI;
    int l = (idx / DI) % LL;
    int b = idx / (DI * LL);
    float acc = cb[c];
#pragma unroll
    for (int j = 0; j < DCONV; j++) {
        int lt = l - (DCONV - 1) + j;
        if (lt >= 0) acc += xz[((size_t)(b * LL + lt)) * (2 * DI) + c] * cw[c * DCONV + j];
    }
    xc[idx] = siluf(acc);
}

// ---------------------------------------------------------------- chunk-parallel selective scan
// one block per (b, 2 d-channels). L=128 split into 8 chunks of 16.
// phase 0: delta (1 thread per (t,d), no reduce) + stage a=exp(d*A), du, u, B, C, silu(z) in LDS
// phase 1: per (s,d,chunk) local recurrence from h=0; save carries (A-prod, h-local)
// phase 1.5: 32 threads combine carries serially over 8 chunks
// phase 2: replay with true h-start; s-reduce via shfl; write y.
__global__ __launch_bounds__(256) void k_scan(
    const float* __restrict__ xdbl, const float* __restrict__ xc,
    const float* __restrict__ xz,
    const float* __restrict__ dtw, const float* __restrict__ dtb,
    const float* __restrict__ Alog, const float* __restrict__ Dp,
    float* __restrict__ y)
{
    const int tid = threadIdx.x;
    const int b = blockIdx.x / (DI / 2);
    const int d0 = (blockIdx.x % (DI / 2)) * 2;

    __shared__ float da[LL][33];      // [t][2*s+dl], padded stride 33
    __shared__ float Bsh[LL][DS];
    __shared__ float Csh[LL][DS];
    __shared__ float dus[LL][2];
    __shared__ float us[LL][2];
    __shared__ float zs[LL][2];
    __shared__ float ApL[2][DS][9];
    __shared__ float HlL[2][DS][9];
    __shared__ float hst[2][DS][9];

    // ---- phase 0a: thread = (t, dl)
    {
        const int t = tid >> 1, dl = tid & 1;
        const int d = d0 + dl;
        const size_t row = (size_t)b * LL + t;
        const float* xd = xdbl + row * XROW;
        const float* w = dtw + d * DTR;
        float acc = dtb[d];
#pragma unroll
        for (int k = 0; k < DTR; k++) acc += xd[k] * w[k];
        float delta = fmaxf(acc, 0.f) + log1pf(__expf(-fabsf(acc)));  // softplus
        float u = xc[row * DI + d];
        dus[t][dl] = delta * u;
        us[t][dl] = u;
        zs[t][dl] = siluf(xz[row * (2 * DI) + DI + d]);
#pragma unroll
        for (int s = 0; s < DS; s++)
            da[t][2 * s + dl] = __expf(delta * (-__expf(Alog[d * DS + s])));
    }
    // ---- phase 0b: stage B, C
    for (int i = tid; i < LL * DS; i += 256) {
        int t = i >> 4, s = i & 15;
        const float* xd = xdbl + ((size_t)b * LL + t) * XROW;
        Bsh[t][s] = xd[DTR + s];
        Csh[t][s] = xd[DTR + DS + s];
    }
    __syncthreads();

    const int s = tid & 15;
    const int dl = (tid >> 4) & 1;
    const int c = tid >> 5;           // chunk 0..7

    // ---- phase 1: local recurrence, h0 = 0
    {
        float h = 0.f, Ap = 1.f;
#pragma unroll
        for (int q = 0; q < 16; q++) {
            int t = c * 16 + q;
            float a = da[t][2 * s + dl];
            h = h * a + dus[t][dl] * Bsh[t][s];
            Ap *= a;
        }
        ApL[dl][s][c] = Ap;
        HlL[dl][s][c] = h;
    }
    __syncthreads();
    // ---- phase 1.5: combine carries
    if (tid < 32) {
        int s2 = tid & 15, d2 = tid >> 4;
        float hs = 0.f;
#pragma unroll
        for (int cc = 0; cc < 8; cc++) {
            hst[d2][s2][cc] = hs;
            hs = ApL[d2][s2][cc] * hs + HlL[d2][s2][cc];
        }
    }
    __syncthreads();

    // ---- phase 2: replay with true h-start, reduce over s, write y
    {
        const float Dd = Dp[d0 + dl];
        float h = hst[dl][s][c];
        float* yc = y + ((size_t)b * LL + c * 16) * DI + (d0 + dl);
#pragma unroll
        for (int q = 0; q < 16; q++) {
            int t = c * 16 + q;
            float a = da[t][2 * s + dl];
            h = h * a + dus[t][dl] * Bsh[t][s];
            float p = h * Csh[t][s];
            p += __shfl_xor(p, 1, 16);
            p += __shfl_xor(p, 2, 16);
            p += __shfl_xor(p, 4, 16);
            p += __shfl_xor(p, 8, 16);
            if (s == 0) yc[(size_t)q * DI] = (p + Dd * us[t][dl]) * zs[t][dl];
        }
    }
}

// ---------------------------------------------------------------- final layernorm (wave per row)
__global__ __launch_bounds__(64) void k_ln(const float* __restrict__ x,
                                           const float* __restrict__ g,
                                           const float* __restrict__ bb,
                                           float* __restrict__ y)
{
    const int row = blockIdx.x;
    const int tid = threadIdx.x;
    const float* xr = x + (size_t)row * DD;
    float v[6];
    float s = 0.f;
#pragma unroll
    for (int j = 0; j < 6; j++) { v[j] = xr[tid + 64 * j]; s += v[j]; }
#pragma unroll
    for (int off = 32; off; off >>= 1) s += __shfl_xor(s, off);
    float mean = s * (1.0f / DD);
    float vs = 0.f;
#pragma unroll
    for (int j = 0; j < 6; j++) { float dd = v[j] - mean; vs += dd * dd; }
#pragma unroll
    for (int off = 32; off; off >>= 1) vs += __shfl_xor(vs, off);
    float inv = 1.0f / sqrtf(vs * (1.0f / DD) + 1e-5f);
#pragma unroll
    for (int j = 0; j < 6; j++) {
        int i = tid + 64 * j;
        y[(size_t)row * DD + i] = (v[j] - mean) * inv * g[i] + bb[i];
    }
}

// ---------------------------------------------------------------- mean over L
__global__ void k_mean(const float* __restrict__ xln, float* __restrict__ pooled)
{
    int idx = blockIdx.x * blockDim.x + threadIdx.x;
    if (idx >= BB * DD) return;
    int b = idx / DD, d = idx % DD;
    float sv = 0.f;
    for (int l = 0; l < LL; l++) sv += xln[((size_t)b * LL + l) * DD + d];
    pooled[idx] = sv / (float)LL;
}

// ---------------------------------------------------------------- head MLP (one block per batch)
__global__ __launch_bounds__(256) void k_mlp(const float* __restrict__ pooled,
    const float* __restrict__ w1, const float* __restrict__ b1,
    const float* __restrict__ w2, const float* __restrict__ b2,
    const float* __restrict__ w3, const float* __restrict__ b3,
    float* __restrict__ out)
{
    int b = blockIdx.x, tid = threadIdx.x;
    __shared__ float pl[DD];
    __shared__ float h1[256];
    __shared__ float h2[64];
    for (int i = tid; i < DD; i += 256) pl[i] = pooled[b * DD + i];
    __syncthreads();
    {
        float acc = b1[tid];
        const float* wr = w1 + (size_t)tid * DD;
        for (int k = 0; k < DD; k++) acc += pl[k] * wr[k];
        h1[tid] = fmaxf(acc, 0.f);
    }
    __syncthreads();
    if (tid < 64) {
        float acc = b2[tid];
        const float* wr = w2 + (size_t)tid * 256;
        for (int k = 0; k < 256; k++) acc += h1[k] * wr[k];
        h2[tid] = fmaxf(acc, 0.f);
    }
    __syncthreads();
    if (tid < NC) {
        float acc = b3[tid];
        const float* wr = w3 + (size_t)tid * 64;
        for (int k = 0; k < 64; k++) acc += h2[k] * wr[k];
        out[b * NC + tid] = acc;
    }
}

// ---------------------------------------------------------------- launch
extern "C" void kernel_launch(void* const* d_in, const int* in_sizes, int n_in,
                              void* d_out, int out_size, void* d_ws, size_t ws_size,
                              hipStream_t stream)
{
    const float* data      = (const float*)d_in[0];
    const float* pe_w1     = (const float*)d_in[1];
    const float* pe_b1     = (const float*)d_in[2];
    const float* pe_g1     = (const float*)d_in[3];
    const float* pe_be1    = (const float*)d_in[4];
    const float* pe_w2     = (const float*)d_in[5];
    const float* pe_b2     = (const float*)d_in[6];
    const float* pe_g2     = (const float*)d_in[7];
    const float* pe_be2    = (const float*)d_in[8];
    const float* pe_w3     = (const float*)d_in[9];
    const float* pe_b3     = (const float*)d_in[10];
    const float* pe_g3     = (const float*)d_in[11];
    const float* pe_be3    = (const float*)d_in[12];
    const float* oi_h_scale  = (const float*)d_in[13];
    const float* oi_h_shift  = (const float*)d_in[14];
    const float* oi_th_scale = (const float*)d_in[15];
    const float* oi_th_shift = (const float*)d_in[16];
    const float* pos_embed = (const float*)d_in[17];
    const float* blk_ln_g  = (const float*)d_in[18];
    const float* blk_ln_b  = (const float*)d_in[19];
    const float* blk_in_w  = (const float*)d_in[20];
    const float* blk_conv_w = (const float*)d_in[21];
    const float* blk_conv_b = (const float*)d_in[22];
    const float* blk_xp_w  = (const float*)d_in[23];
    const float* blk_dt_w  = (const float*)d_in[24];
    const float* blk_dt_b  = (const float*)d_in[25];
    const float* blk_Alog  = (const float*)d_in[26];
    const float* blk_D     = (const float*)d_in[27];
    const float* blk_out_w = (const float*)d_in[28];
    const float* norm_g    = (const float*)d_in[29];
    const float* norm_b    = (const float*)d_in[30];
    const float* mlp_w1    = (const float*)d_in[31];
    const float* mlp_b1    = (const float*)d_in[32];
    const float* mlp_w2    = (const float*)d_in[33];
    const float* mlp_b2    = (const float*)d_in[34];
    const float* mlp_w3    = (const float*)d_in[35];
    const float* mlp_b3    = (const float*)d_in[36];

    float* ws = (float*)d_ws;
    size_t off = 0;
    auto alloc = [&](size_t n) { float* p = ws + off; off += (n + 63) & ~(size_t)63; return p; };
    float* tokens  = alloc((size_t)BB * PP * DD);
    float* centers = alloc((size_t)BB * PP * 3);
    int*   order_h = (int*)alloc((size_t)BB * PP);
    int*   order_th= (int*)alloc((size_t)BB * PP);
    int*   knn_idx = (int*)alloc((size_t)BB * PP * KK);
    float* t    = alloc((size_t)NR * DD);
    float* xln  = alloc((size_t)NR * DD);
    float* xz   = alloc((size_t)NR * 2 * DI);
    float* xc   = alloc((size_t)NR * DI);
    float* xdbl = alloc((size_t)NR * XROW);
    float* yb   = alloc((size_t)NR * DI);
    float* rmean= alloc(NR);
    float* rinv = alloc(NR);
    float* pooled = alloc((size_t)BB * DD);

    k_knn<<<BB * PP, 256, 0, stream>>>(data, knn_idx, centers);
    k_pe_mlp<<<BB * PP, 256, 0, stream>>>(data, knn_idx,
        pe_w1, pe_b1, pe_g1, pe_be1, pe_w2, pe_b2, pe_g2, pe_be2,
        pe_w3, pe_b3, pe_g3, pe_be3, tokens);
    k_sfc<<<BB, 64, 0, stream>>>(centers, order_h, order_th);
    {
        int nt = BB * LL * DD;
        k_build_t<<<(nt + 255) / 256, 256, 0, stream>>>(tokens, order_h, order_th,
            oi_h_scale, oi_h_shift, oi_th_scale, oi_th_shift, pos_embed, t);
    }

    for (int i = 0; i < DEPTH; i++) {
        const float* ln_g = blk_ln_g + i * DD;
        const float* ln_b = blk_ln_b + i * DD;
        const float* in_w = blk_in_w + (size_t)i * 2 * DI * DD;
        const float* cw   = blk_conv_w + (size_t)i * DI * DCONV;
        const float* cb   = blk_conv_b + (size_t)i * DI;
        const float* xp   = blk_xp_w + (size_t)i * XROW * DI;
        const float* dtw  = blk_dt_w + (size_t)i * DI * DTR;
        const float* dtb  = blk_dt_b + (size_t)i * DI;
        const float* Al   = blk_Alog + (size_t)i * DI * DS;
        const float* Dpp  = blk_D + (size_t)i * DI;
        const float* ow   = blk_out_w + (size_t)i * DD * DI;

        k_stats<<<NR / 4, 256, 0, stream>>>(t, rmean, rinv, xdbl);
        k_gemm128<1, 0><<<dim3(2 * DI / 128, NR / 64, 1), 256, 0, stream>>>(
            t, DD, in_w, DD, rmean, rinv, ln_g, ln_b, xz, 2 * DI, DD);
        k_conv<<<(NR * DI + 255) / 256, 256, 0, stream>>>(xz, cw, cb, xc);
        k_gemm64<1><<<dim3(1, NR / 64, 4), 256, 0, stream>>>(
            xc, DI, xp, DI, xdbl, XROW, NR, XROW, DI, DI / 4);
        k_scan<<<BB * DI / 2, 256, 0, stream>>>(xdbl, xc, xz, dtw, dtb, Al, Dpp, yb);
        k_gemm128<0, 1><<<dim3(DD / 128, NR / 64, 4), 256, 0, stream>>>(
            yb, DI, ow, DI, nullptr, nullptr, nullptr, nullptr, t, DD, DI / 4);
    }

    k_ln<<<NR, 64, 0, stream>>>(t, norm_g, norm_b, xln);
    k_mean<<<(BB * DD + 255) / 256, 256, 0, stream>>>(xln, pooled);
    k_mlp<<<BB, 256, 0, stream>>>(pooled, mlp_w1, mlp_b1, mlp_w2, mlp_b2, mlp_w3, mlp_b3,
                                  (float*)d_out);
}

// Round 5
// 1508.802 us; speedup vs baseline: 2.4874x; 1.5030x over previous
//
#include <hip/hip_runtime.h>
#include <math.h>

#define BB 8
#define NN 2048
#define PP 64
#define KK 32
#define DD 384
#define DEPTH 12
#define DI 768
#define DS 16
#define DCONV 4
#define DTR 24
#define NC 40
#define LL 128  // 2*PP
#define XROW (DTR + 2 * DS)  // 56
#define NR (BB * LL)         // 1024
#define XZSPLIT 12           // split-K for xdbl gemm

// ---------------------------------------------------------------- helpers
__device__ __forceinline__ float gelu_exact(float x) {
    return 0.5f * x * (1.0f + erff(x * 0.70710678118654752440f));
}
__device__ __forceinline__ float siluf(float x) {
    return x / (1.0f + expf(-x));
}
__device__ __forceinline__ unsigned spread_bits(unsigned v) {
    v &= 1023u;
    v = (v | (v << 16)) & 50331903u;
    v = (v | (v << 8)) & 50393103u;
    v = (v | (v << 4)) & 51130563u;
    v = (v | (v << 2)) & 153391689u;
    return v;
}

// ---------------------------------------------------------------- KNN: one block per (b,p)
__global__ __launch_bounds__(256) void k_knn(const float* __restrict__ data,
                                             int* __restrict__ knn_out,
                                             float* __restrict__ centers)
{
    const int bp = blockIdx.x;
    const int b = bp >> 6, p = bp & 63;
    const int tid = threadIdx.x;
    const int lane = tid & 63, wid = tid >> 6;
    const float* X = data + (size_t)b * NN * 3;

    const float cx = X[p * 32 * 3 + 0];
    const float cy = X[p * 32 * 3 + 1];
    const float cz = X[p * 32 * 3 + 2];
    if (tid == 0) {
        centers[(b * PP + p) * 3 + 0] = cx;
        centers[(b * PP + p) * 3 + 1] = cy;
        centers[(b * PP + p) * 3 + 2] = cz;
    }

    unsigned long long pk[8];
#pragma unroll
    for (int q = 0; q < 8; q++) {
        int i = tid + 256 * q;
        float dx = cx - X[i * 3 + 0];
        float dy = cy - X[i * 3 + 1];
        float dz = cz - X[i * 3 + 2];
        float d2 = dx * dx + dy * dy + dz * dz;
        pk[q] = ((unsigned long long)__float_as_uint(d2) << 32) | (unsigned)i;
    }

    __shared__ unsigned long long wred[4];
    __shared__ int klist[KK];
    for (int k = 0; k < KK; k++) {
        unsigned long long m = pk[0];
#pragma unroll
        for (int q = 1; q < 8; q++) m = pk[q] < m ? pk[q] : m;
#pragma unroll
        for (int off = 32; off; off >>= 1) {
            unsigned long long o = __shfl_xor(m, off);
            m = o < m ? o : m;
        }
        if (lane == 0) wred[wid] = m;
        __syncthreads();
        unsigned long long g = wred[0];
#pragma unroll
        for (int w = 1; w < 4; w++) g = wred[w] < g ? wred[w] : g;
#pragma unroll
        for (int q = 0; q < 8; q++)
            if (pk[q] == g) pk[q] = ~0ull;
        if (tid == 0) klist[k] = (int)(g & 0xffffffffu);
        __syncthreads();
    }
    if (tid < KK) knn_out[bp * KK + tid] = klist[tid];
}

// ---------------------------------------------------------------- patch-embed MLP: one block per (b,p)
__global__ __launch_bounds__(256) void k_pe_mlp(
    const float* __restrict__ data, const int* __restrict__ knn_in,
    const float* __restrict__ w1, const float* __restrict__ b1,
    const float* __restrict__ g1, const float* __restrict__ be1,
    const float* __restrict__ w2, const float* __restrict__ b2,
    const float* __restrict__ g2, const float* __restrict__ be2,
    const float* __restrict__ w3, const float* __restrict__ b3,
    const float* __restrict__ g3, const float* __restrict__ be3,
    float* __restrict__ tokens)
{
    const int bp = blockIdx.x;
    const int b = bp >> 6, p = bp & 63;
    const int tid = threadIdx.x;
    const float* X = data + (size_t)b * NN * 3;
    const float inv_den = 0.99999500003749968752f; // 1/sqrt(1+1e-5)

    __shared__ float nxs[KK * 3];
    __shared__ float h1s[KK * 64];
    __shared__ float h2s[KK * 136];

    const float cx = X[p * 32 * 3 + 0];
    const float cy = X[p * 32 * 3 + 1];
    const float cz = X[p * 32 * 3 + 2];
    if (tid < KK) {
        int q = knn_in[bp * KK + tid];
        nxs[tid * 3 + 0] = X[q * 3 + 0] - cx;
        nxs[tid * 3 + 1] = X[q * 3 + 1] - cy;
        nxs[tid * 3 + 2] = X[q * 3 + 2] - cz;
    }
    __syncthreads();

    for (int e = tid; e < KK * 64; e += 256) {
        int j = e >> 6, c = e & 63;
        float v = nxs[j * 3 + 0] * w1[c * 3 + 0] + nxs[j * 3 + 1] * w1[c * 3 + 1] +
                  nxs[j * 3 + 2] * w1[c * 3 + 2] + b1[c];
        v = v * (g1[c] * inv_den) + be1[c];
        h1s[j * 64 + c] = gelu_exact(v);
    }
    __syncthreads();

    for (int e = tid; e < KK * 128; e += 256) {
        int j = e >> 7, c = e & 127;
        const float4* wr = (const float4*)(w2 + (size_t)c * 64);
        const float4* hr = (const float4*)(h1s + j * 64);
        float acc = 0.f;
#pragma unroll
        for (int q = 0; q < 16; q++) {
            float4 wv = wr[q], hv = hr[q];
            acc += hv.x * wv.x + hv.y * wv.y + hv.z * wv.z + hv.w * wv.w;
        }
        float v = (acc + b2[c]) * (g2[c] * inv_den) + be2[c];
        h2s[j * 136 + c] = gelu_exact(v);
    }
    __syncthreads();

    const int cg = tid >> 2;
    const int jg = tid & 3;
    const int c0 = cg * 6;
    float acc[6][8];
#pragma unroll
    for (int i = 0; i < 6; i++)
#pragma unroll
        for (int j = 0; j < 8; j++) acc[i][j] = 0.f;

    for (int q = 0; q < 32; q++) {
        float4 hv[8];
#pragma unroll
        for (int jj = 0; jj < 8; jj++)
            hv[jj] = *(const float4*)(h2s + (jg + 4 * jj) * 136 + q * 4);
#pragma unroll
        for (int ci = 0; ci < 6; ci++) {
            float4 wv = *(const float4*)(w3 + (size_t)(c0 + ci) * 128 + q * 4);
#pragma unroll
            for (int jj = 0; jj < 8; jj++) {
                acc[ci][jj] += hv[jj].x * wv.x + hv[jj].y * wv.y +
                               hv[jj].z * wv.z + hv[jj].w * wv.w;
            }
        }
    }
#pragma unroll
    for (int ci = 0; ci < 6; ci++) {
        int c = c0 + ci;
        float bi = b3[c], sc = g3[c] * inv_den, sh = be3[c];
        float m = -3.4e38f;
#pragma unroll
        for (int jj = 0; jj < 8; jj++)
            m = fmaxf(m, (acc[ci][jj] + bi) * sc + sh);
        m = fmaxf(m, __shfl_xor(m, 1, 4));
        m = fmaxf(m, __shfl_xor(m, 2, 4));
        if (jg == 0) tokens[((size_t)b * PP + p) * DD + c] = m;
    }
}

// ---------------------------------------------------------------- SFC orders
__global__ __launch_bounds__(64) void k_sfc(const float* __restrict__ centers,
                                            int* __restrict__ order_h,
                                            int* __restrict__ order_th)
{
    const int b = blockIdx.x;
    const int tid = threadIdx.x;
    float cc[3];
    cc[0] = centers[(b * PP + tid) * 3 + 0];
    cc[1] = centers[(b * PP + tid) * 3 + 1];
    cc[2] = centers[(b * PP + tid) * 3 + 2];

    __shared__ float csh[PP][3];
    __shared__ float slo[3], shi[3];
    csh[tid][0] = cc[0]; csh[tid][1] = cc[1]; csh[tid][2] = cc[2];
    __syncthreads();
    if (tid == 0) {
        for (int k = 0; k < 3; k++) {
            float lo = csh[0][k], hi = csh[0][k];
            for (int j = 1; j < PP; j++) { lo = fminf(lo, csh[j][k]); hi = fmaxf(hi, csh[j][k]); }
            slo[k] = lo; shi[k] = hi;
        }
    }
    __syncthreads();

    int q[3];
    for (int k = 0; k < 3; k++) {
        float t = (cc[k] - slo[k]) / (shi[k] - slo[k] + 1e-6f) * 1023.0f;
        int qi = (int)t;
        qi = qi < 0 ? 0 : (qi > 1023 ? 1023 : qi);
        q[k] = qi;
    }
    unsigned kh = spread_bits((unsigned)q[0]) | (spread_bits((unsigned)q[1]) << 1) |
                  (spread_bits((unsigned)q[2]) << 2);
    unsigned kt = spread_bits((unsigned)q[2]) | (spread_bits((unsigned)q[1]) << 1) |
                  (spread_bits((unsigned)q[0]) << 2);

    __shared__ unsigned khs[PP], kts[PP];
    khs[tid] = kh; kts[tid] = kt;
    __syncthreads();
    int rh = 0, rt = 0;
    for (int j = 0; j < PP; j++) {
        unsigned a = khs[j];
        rh += (a < kh) || (a == kh && j < tid);
        unsigned c = kts[j];
        rt += (c < kt) || (c == kt && j < tid);
    }
    order_h[b * PP + rh] = tid;
    order_th[b * PP + rt] = tid;
}

// ---------------------------------------------------------------- build token sequence
__global__ void k_build_t(const float* __restrict__ tokens,
                          const int* __restrict__ order_h, const int* __restrict__ order_th,
                          const float* __restrict__ hs, const float* __restrict__ hb,
                          const float* __restrict__ ts, const float* __restrict__ tb,
                          const float* __restrict__ pos, float* __restrict__ t)
{
    int idx = blockIdx.x * blockDim.x + threadIdx.x;
    if (idx >= BB * LL * DD) return;
    int d = idx % DD;
    int l = (idx / DD) % LL;
    int b = idx / (DD * LL);
    float v;
    if (l < PP) {
        int src = order_h[b * PP + l];
        v = tokens[((size_t)b * PP + src) * DD + d] * hs[d] + hb[d] + pos[l * DD + d];
    } else {
        int ll2 = l - PP;
        int src = order_th[b * PP + ll2];
        v = tokens[((size_t)b * PP + src) * DD + d] * ts[d] + tb[d] + pos[ll2 * DD + d];
    }
    t[idx] = v;
}

// ---------------------------------------------------------------- residual-accumulate + LN stats
// t += sum of 4 out-proj partial slices (if parts != null), write t back, compute row stats.
__global__ __launch_bounds__(256) void k_stats(float* __restrict__ t,
                                               const float* __restrict__ parts,
                                               float* __restrict__ rmean,
                                               float* __restrict__ rinv)
{
    const int tid = threadIdx.x;
    const int wid = tid >> 6, lane = tid & 63;
    const int row = blockIdx.x * 4 + wid;
    const size_t base = (size_t)row * DD;
    float v[6];
    float s = 0.f;
#pragma unroll
    for (int j = 0; j < 6; j++) {
        int i = lane + 64 * j;
        float x = t[base + i];
        if (parts) {
            x += parts[base + i] + parts[(size_t)NR * DD + base + i] +
                 parts[2 * (size_t)NR * DD + base + i] + parts[3 * (size_t)NR * DD + base + i];
            t[base + i] = x;
        }
        v[j] = x; s += x;
    }
#pragma unroll
    for (int off = 32; off; off >>= 1) s += __shfl_xor(s, off);
    float mean = s * (1.0f / DD);
    float vs = 0.f;
#pragma unroll
    for (int j = 0; j < 6; j++) { float dd = v[j] - mean; vs += dd * dd; }
#pragma unroll
    for (int off = 32; off; off >>= 1) vs += __shfl_xor(vs, off);
    float inv = 1.0f / sqrtf(vs * (1.0f / DD) + 1e-5f);
    if (lane == 0) { rmean[row] = mean; rinv[row] = inv; }
}

// ---------------------------------------------------------------- 64x128-tile fp32 GEMM, micro 4x(4+4)
// C[M,N] = A[M,K]*B[N,K]^T; per-z output slice C + z*cstride (plain stores, no atomics).
// Cols per thread: {tx*4..+3} and {64+tx*4..+3}  -> 2-way LDS banks (free).
// Global->register prefetch double-buffer.
template <int NORM>
__global__ __launch_bounds__(256) void k_gemm128(
    const float* __restrict__ A, int lda,
    const float* __restrict__ B, int ldb,
    const float* __restrict__ rmean, const float* __restrict__ rinv,
    const float* __restrict__ g, const float* __restrict__ gb,
    float* __restrict__ C, int ldc, size_t cstride,
    int kchunk)
{
    __shared__ float As[16][68];
    __shared__ float Bs[16][132];   // 132: 4*132 % 32 == 16 -> staging 2-way (free)
    const int tid = threadIdx.x;
    const int tx = tid & 15;
    const int ty = tid >> 4;
    const int m0 = blockIdx.y * 64, n0 = blockIdx.x * 128;
    const int kbeg = blockIdx.z * kchunk;
    const int kend = kbeg + kchunk;
    float* Cz = C + (size_t)blockIdx.z * cstride;

    const int lm = tid >> 2;
    const int lk = (tid & 3) * 4;

    const float* Arow  = A + (size_t)(m0 + lm) * lda;
    const float* Brow0 = B + (size_t)(n0 + lm) * ldb;
    const float* Brow1 = B + (size_t)(n0 + 64 + lm) * ldb;
    float mea = 0.f, inv = 0.f;
    if (NORM) { mea = rmean[m0 + lm]; inv = rinv[m0 + lm]; }

    float acc[4][8];
#pragma unroll
    for (int i = 0; i < 4; i++)
#pragma unroll
        for (int j = 0; j < 8; j++) acc[i][j] = 0.f;

    float4 av = *(const float4*)(Arow + kbeg + lk);
    float4 b0 = *(const float4*)(Brow0 + kbeg + lk);
    float4 b1 = *(const float4*)(Brow1 + kbeg + lk);

    for (int k0 = kbeg; k0 < kend; k0 += 16) {
        const int an = (k0 + 16 < kend) ? (k0 + 16 + lk) : (kbeg + lk);
        float4 nav = *(const float4*)(Arow + an);
        float4 nb0 = *(const float4*)(Brow0 + an);
        float4 nb1 = *(const float4*)(Brow1 + an);

        float4 sv = av;
        if (NORM) {
            int ak = k0 + lk;
            float4 gv = *(const float4*)(g + ak);
            float4 bv = *(const float4*)(gb + ak);
            sv.x = (sv.x - mea) * inv * gv.x + bv.x;
            sv.y = (sv.y - mea) * inv * gv.y + bv.y;
            sv.z = (sv.z - mea) * inv * gv.z + bv.z;
            sv.w = (sv.w - mea) * inv * gv.w + bv.w;
        }
        As[lk + 0][lm] = sv.x; As[lk + 1][lm] = sv.y; As[lk + 2][lm] = sv.z; As[lk + 3][lm] = sv.w;
        Bs[lk + 0][lm] = b0.x; Bs[lk + 1][lm] = b0.y; Bs[lk + 2][lm] = b0.z; Bs[lk + 3][lm] = b0.w;
        Bs[lk + 0][64 + lm] = b1.x; Bs[lk + 1][64 + lm] = b1.y;
        Bs[lk + 2][64 + lm] = b1.z; Bs[lk + 3][64 + lm] = b1.w;
        __syncthreads();
#pragma unroll
        for (int kk = 0; kk < 16; kk++) {
            float4 a  = *(const float4*)(&As[kk][ty * 4]);
            float4 bA = *(const float4*)(&Bs[kk][tx * 4]);
            float4 bB = *(const float4*)(&Bs[kk][64 + tx * 4]);
            acc[0][0] += a.x * bA.x; acc[0][1] += a.x * bA.y; acc[0][2] += a.x * bA.z; acc[0][3] += a.x * bA.w;
            acc[0][4] += a.x * bB.x; acc[0][5] += a.x * bB.y; acc[0][6] += a.x * bB.z; acc[0][7] += a.x * bB.w;
            acc[1][0] += a.y * bA.x; acc[1][1] += a.y * bA.y; acc[1][2] += a.y * bA.z; acc[1][3] += a.y * bA.w;
            acc[1][4] += a.y * bB.x; acc[1][5] += a.y * bB.y; acc[1][6] += a.y * bB.z; acc[1][7] += a.y * bB.w;
            acc[2][0] += a.z * bA.x; acc[2][1] += a.z * bA.y; acc[2][2] += a.z * bA.z; acc[2][3] += a.z * bA.w;
            acc[2][4] += a.z * bB.x; acc[2][5] += a.z * bB.y; acc[2][6] += a.z * bB.z; acc[2][7] += a.z * bB.w;
            acc[3][0] += a.w * bA.x; acc[3][1] += a.w * bA.y; acc[3][2] += a.w * bA.z; acc[3][3] += a.w * bA.w;
            acc[3][4] += a.w * bB.x; acc[3][5] += a.w * bB.y; acc[3][6] += a.w * bB.z; acc[3][7] += a.w * bB.w;
        }
        __syncthreads();
        av = nav; b0 = nb0; b1 = nb1;
    }

    const int crow = m0 + ty * 4;
    const int ccol = n0 + tx * 4;
#pragma unroll
    for (int i = 0; i < 4; i++) {
        float* cp = Cz + (size_t)(crow + i) * ldc + ccol;
        *(float4*)cp        = make_float4(acc[i][0], acc[i][1], acc[i][2], acc[i][3]);
        *(float4*)(cp + 64) = make_float4(acc[i][4], acc[i][5], acc[i][6], acc[i][7]);
    }
}

// ---------------------------------------------------------------- xdbl GEMM with fused causal conv+SiLU
// parts[z][NR][XROW] = silu(conv(xz))[.,kchunk slice] @ xp^T ; z = 0..XZSPLIT-1, kchunk=64.
__global__ __launch_bounds__(256) void k_gemm_xdbl(
    const float* __restrict__ xz, const float* __restrict__ cw, const float* __restrict__ cb,
    const float* __restrict__ xp, float* __restrict__ parts, int kchunk)
{
    __shared__ float As[16][68];
    __shared__ float Bs[16][68];
    __shared__ float cwL[64][4];
    __shared__ float cbL[64];
    const int tid = threadIdx.x;
    const int tx = tid & 15, ty = tid >> 4;
    const int m0 = blockIdx.y * 64;
    const int z = blockIdx.z;
    const int kbeg = z * kchunk;

    if (tid < 64) {
        cbL[tid] = cb[kbeg + tid];
        *(float4*)cwL[tid] = *(const float4*)(cw + (size_t)(kbeg + tid) * 4);
    }
    __syncthreads();

    const int lm = tid >> 2;
    const int lk = (tid & 3) * 4;
    const int l = (m0 + lm) & (LL - 1);
    const float* xzrow = xz + (size_t)(m0 + lm) * (2 * DI);

    float acc[4][4] = {};

    for (int k0 = kbeg; k0 < kbeg + kchunk; k0 += 16) {
        const int ak = k0 + lk;
        const int cl = ak - kbeg;       // local channel 0..63
        float4 a = make_float4(cbL[cl + 0], cbL[cl + 1], cbL[cl + 2], cbL[cl + 3]);
#pragma unroll
        for (int j = 0; j < DCONV; j++) {
            int lt = l - (DCONV - 1) + j;
            if (lt >= 0) {
                float4 xv = *(const float4*)(xzrow + (size_t)(lt - l) * (2 * DI) + ak);
                a.x += xv.x * cwL[cl + 0][j];
                a.y += xv.y * cwL[cl + 1][j];
                a.z += xv.z * cwL[cl + 2][j];
                a.w += xv.w * cwL[cl + 3][j];
            }
        }
        a.x = siluf(a.x); a.y = siluf(a.y); a.z = siluf(a.z); a.w = siluf(a.w);

        float4 bv = make_float4(0.f, 0.f, 0.f, 0.f);
        if (lm < XROW) bv = *(const float4*)(xp + (size_t)lm * DI + ak);

        As[lk + 0][lm] = a.x; As[lk + 1][lm] = a.y; As[lk + 2][lm] = a.z; As[lk + 3][lm] = a.w;
        Bs[lk + 0][lm] = bv.x; Bs[lk + 1][lm] = bv.y; Bs[lk + 2][lm] = bv.z; Bs[lk + 3][lm] = bv.w;
        __syncthreads();
#pragma unroll
        for (int kk = 0; kk < 16; kk++) {
            float4 a2 = *(const float4*)(&As[kk][ty * 4]);
            float4 b2 = *(const float4*)(&Bs[kk][tx * 4]);
            acc[0][0] += a2.x * b2.x; acc[0][1] += a2.x * b2.y; acc[0][2] += a2.x * b2.z; acc[0][3] += a2.x * b2.w;
            acc[1][0] += a2.y * b2.x; acc[1][1] += a2.y * b2.y; acc[1][2] += a2.y * b2.z; acc[1][3] += a2.y * b2.w;
            acc[2][0] += a2.z * b2.x; acc[2][1] += a2.z * b2.y; acc[2][2] += a2.z * b2.z; acc[2][3] += a2.z * b2.w;
            acc[3][0] += a2.w * b2.x; acc[3][1] += a2.w * b2.y; acc[3][2] += a2.w * b2.z; acc[3][3] += a2.w * b2.w;
        }
        __syncthreads();
    }

    const int crow = m0 + ty * 4;
    const int ccol = tx * 4;
    if (ccol < XROW) {
        float* out = parts + (size_t)z * NR * XROW;
#pragma unroll
        for (int i = 0; i < 4; i++) {
            float* cp = out + (size_t)(crow + i) * XROW + ccol;
            *(float4*)cp = make_float4(acc[i][0], acc[i][1], acc[i][2], acc[i][3]);
        }
    }
}

// ---------------------------------------------------------------- reduce xdbl partials
__global__ void k_xred(const float* __restrict__ parts, float* __restrict__ xdbl)
{
    int i = blockIdx.x * 256 + threadIdx.x;
    if (i >= NR * XROW) return;
    float s = 0.f;
#pragma unroll
    for (int z = 0; z < XZSPLIT; z++) s += parts[(size_t)z * NR * XROW + i];
    xdbl[i] = s;
}

// ---------------------------------------------------------------- chunk-parallel selective scan
// one block per (b, 2 d-channels); u recomputed from xz via fused conv.
__global__ __launch_bounds__(256) void k_scan(
    const float* __restrict__ xdbl, const float* __restrict__ xz,
    const float* __restrict__ cw, const float* __restrict__ cb,
    const float* __restrict__ dtw, const float* __restrict__ dtb,
    const float* __restrict__ Alog, const float* __restrict__ Dp,
    float* __restrict__ y)
{
    const int tid = threadIdx.x;
    const int b = blockIdx.x / (DI / 2);
    const int d0 = (blockIdx.x % (DI / 2)) * 2;

    __shared__ float da[LL][33];
    __shared__ float Bsh[LL][DS];
    __shared__ float Csh[LL][DS];
    __shared__ float dus[LL][2];
    __shared__ float us[LL][2];
    __shared__ float zs[LL][2];
    __shared__ float ApL[2][DS][9];
    __shared__ float HlL[2][DS][9];
    __shared__ float hst[2][DS][9];

    // ---- phase 0a: thread = (t, dl): delta (K=24 dot) + conv for u + gate
    {
        const int t = tid >> 1, dl = tid & 1;
        const int d = d0 + dl;
        const size_t row = (size_t)b * LL + t;
        const float* xd = xdbl + row * XROW;
        const float* w = dtw + d * DTR;
        float acc = dtb[d];
#pragma unroll
        for (int k = 0; k < DTR; k++) acc += xd[k] * w[k];
        float delta = fmaxf(acc, 0.f) + log1pf(__expf(-fabsf(acc)));  // softplus
        float u = cb[d];
#pragma unroll
        for (int j = 0; j < DCONV; j++) {
            int lt = t - (DCONV - 1) + j;
            if (lt >= 0) u += xz[((size_t)b * LL + lt) * (2 * DI) + d] * cw[d * DCONV + j];
        }
        u = siluf(u);
        dus[t][dl] = delta * u;
        us[t][dl] = u;
        zs[t][dl] = siluf(xz[row * (2 * DI) + DI + d]);
#pragma unroll
        for (int s = 0; s < DS; s++)
            da[t][2 * s + dl] = __expf(delta * (-__expf(Alog[d * DS + s])));
    }
    // ---- phase 0b: stage B, C
    for (int i = tid; i < LL * DS; i += 256) {
        int t = i >> 4, s = i & 15;
        const float* xd = xdbl + ((size_t)b * LL + t) * XROW;
        Bsh[t][s] = xd[DTR + s];
        Csh[t][s] = xd[DTR + DS + s];
    }
    __syncthreads();

    const int s = tid & 15;
    const int dl = (tid >> 4) & 1;
    const int c = tid >> 5;

    // ---- phase 1: local recurrence, h0 = 0
    {
        float h = 0.f, Ap = 1.f;
#pragma unroll
        for (int q = 0; q < 16; q++) {
            int t = c * 16 + q;
            float a = da[t][2 * s + dl];
            h = h * a + dus[t][dl] * Bsh[t][s];
            Ap *= a;
        }
        ApL[dl][s][c] = Ap;
        HlL[dl][s][c] = h;
    }
    __syncthreads();
    // ---- phase 1.5: combine carries
    if (tid < 32) {
        int s2 = tid & 15, d2 = tid >> 4;
        float hs = 0.f;
#pragma unroll
        for (int cc = 0; cc < 8; cc++) {
            hst[d2][s2][cc] = hs;
            hs = ApL[d2][s2][cc] * hs + HlL[d2][s2][cc];
        }
    }
    __syncthreads();

    // ---- phase 2: replay with true h-start, reduce over s, write y
    {
        const float Dd = Dp[d0 + dl];
        float h = hst[dl][s][c];
        float* yc = y + ((size_t)b * LL + c * 16) * DI + (d0 + dl);
#pragma unroll
        for (int q = 0; q < 16; q++) {
            int t = c * 16 + q;
            float a = da[t][2 * s + dl];
            h = h * a + dus[t][dl] * Bsh[t][s];
            float p = h * Csh[t][s];
            p += __shfl_xor(p, 1, 16);
            p += __shfl_xor(p, 2, 16);
            p += __shfl_xor(p, 4, 16);
            p += __shfl_xor(p, 8, 16);
            if (s == 0) yc[(size_t)q * DI] = (p + Dd * us[t][dl]) * zs[t][dl];
        }
    }
}

// ---------------------------------------------------------------- final layernorm (wave per row) + residual partials
__global__ __launch_bounds__(64) void k_ln(const float* __restrict__ x,
                                           const float* __restrict__ parts,
                                           const float* __restrict__ g,
                                           const float* __restrict__ bb,
                                           float* __restrict__ y)
{
    const int row = blockIdx.x;
    const int tid = threadIdx.x;
    const size_t base = (size_t)row * DD;
    float v[6];
    float s = 0.f;
#pragma unroll
    for (int j = 0; j < 6; j++) {
        int i = tid + 64 * j;
        float xv = x[base + i] + parts[base + i] + parts[(size_t)NR * DD + base + i] +
                   parts[2 * (size_t)NR * DD + base + i] + parts[3 * (size_t)NR * DD + base + i];
        v[j] = xv; s += xv;
    }
#pragma unroll
    for (int off = 32; off; off >>= 1) s += __shfl_xor(s, off);
    float mean = s * (1.0f / DD);
    float vs = 0.f;
#pragma unroll
    for (int j = 0; j < 6; j++) { float dd = v[j] - mean; vs += dd * dd; }
#pragma unroll
    for (int off = 32; off; off >>= 1) vs += __shfl_xor(vs, off);
    float inv = 1.0f / sqrtf(vs * (1.0f / DD) + 1e-5f);
#pragma unroll
    for (int j = 0; j < 6; j++) {
        int i = tid + 64 * j;
        y[base + i] = (v[j] - mean) * inv * g[i] + bb[i];
    }
}

// ---------------------------------------------------------------- mean over L
__global__ void k_mean(const float* __restrict__ xln, float* __restrict__ pooled)
{
    int idx = blockIdx.x * blockDim.x + threadIdx.x;
    if (idx >= BB * DD) return;
    int b = idx / DD, d = idx % DD;
    float sv = 0.f;
    for (int l = 0; l < LL; l++) sv += xln[((size_t)b * LL + l) * DD + d];
    pooled[idx] = sv / (float)LL;
}

// ---------------------------------------------------------------- head MLP (one block per batch)
__global__ __launch_bounds__(256) void k_mlp(const float* __restrict__ pooled,
    const float* __restrict__ w1, const float* __restrict__ b1,
    const float* __restrict__ w2, const float* __restrict__ b2,
    const float* __restrict__ w3, const float* __restrict__ b3,
    float* __restrict__ out)
{
    int b = blockIdx.x, tid = threadIdx.x;
    __shared__ float pl[DD];
    __shared__ float h1[256];
    __shared__ float h2[64];
    for (int i = tid; i < DD; i += 256) pl[i] = pooled[b * DD + i];
    __syncthreads();
    {
        float acc = b1[tid];
        const float* wr = w1 + (size_t)tid * DD;
        for (int k = 0; k < DD; k++) acc += pl[k] * wr[k];
        h1[tid] = fmaxf(acc, 0.f);
    }
    __syncthreads();
    if (tid < 64) {
        float acc = b2[tid];
        const float* wr = w2 + (size_t)tid * 256;
        for (int k = 0; k < 256; k++) acc += h1[k] * wr[k];
        h2[tid] = fmaxf(acc, 0.f);
    }
    __syncthreads();
    if (tid < NC) {
        float acc = b3[tid];
        const float* wr = w3 + (size_t)tid * 64;
        for (int k = 0; k < 64; k++) acc += h2[k] * wr[k];
        out[b * NC + tid] = acc;
    }
}

// ---------------------------------------------------------------- launch
extern "C" void kernel_launch(void* const* d_in, const int* in_sizes, int n_in,
                              void* d_out, int out_size, void* d_ws, size_t ws_size,
                              hipStream_t stream)
{
    const float* data      = (const float*)d_in[0];
    const float* pe_w1     = (const float*)d_in[1];
    const float* pe_b1     = (const float*)d_in[2];
    const float* pe_g1     = (const float*)d_in[3];
    const float* pe_be1    = (const float*)d_in[4];
    const float* pe_w2     = (const float*)d_in[5];
    const float* pe_b2     = (const float*)d_in[6];
    const float* pe_g2     = (const float*)d_in[7];
    const float* pe_be2    = (const float*)d_in[8];
    const float* pe_w3     = (const float*)d_in[9];
    const float* pe_b3     = (const float*)d_in[10];
    const float* pe_g3     = (const float*)d_in[11];
    const float* pe_be3    = (const float*)d_in[12];
    const float* oi_h_scale  = (const float*)d_in[13];
    const float* oi_h_shift  = (const float*)d_in[14];
    const float* oi_th_scale = (const float*)d_in[15];
    const float* oi_th_shift = (const float*)d_in[16];
    const float* pos_embed = (const float*)d_in[17];
    const float* blk_ln_g  = (const float*)d_in[18];
    const float* blk_ln_b  = (const float*)d_in[19];
    const float* blk_in_w  = (const float*)d_in[20];
    const float* blk_conv_w = (const float*)d_in[21];
    const float* blk_conv_b = (const float*)d_in[22];
    const float* blk_xp_w  = (const float*)d_in[23];
    const float* blk_dt_w  = (const float*)d_in[24];
    const float* blk_dt_b  = (const float*)d_in[25];
    const float* blk_Alog  = (const float*)d_in[26];
    const float* blk_D     = (const float*)d_in[27];
    const float* blk_out_w = (const float*)d_in[28];
    const float* norm_g    = (const float*)d_in[29];
    const float* norm_b    = (const float*)d_in[30];
    const float* mlp_w1    = (const float*)d_in[31];
    const float* mlp_b1    = (const float*)d_in[32];
    const float* mlp_w2    = (const float*)d_in[33];
    const float* mlp_b2    = (const float*)d_in[34];
    const float* mlp_w3    = (const float*)d_in[35];
    const float* mlp_b3    = (const float*)d_in[36];

    float* ws = (float*)d_ws;
    size_t off = 0;
    auto alloc = [&](size_t n) { float* p = ws + off; off += (n + 63) & ~(size_t)63; return p; };
    float* tokens  = alloc((size_t)BB * PP * DD);
    float* centers = alloc((size_t)BB * PP * 3);
    int*   order_h = (int*)alloc((size_t)BB * PP);
    int*   order_th= (int*)alloc((size_t)BB * PP);
    int*   knn_idx = (int*)alloc((size_t)BB * PP * KK);
    float* t    = alloc((size_t)NR * DD);
    float* xln  = alloc((size_t)NR * DD);
    float* xz   = alloc((size_t)NR * 2 * DI);
    float* xdbl = alloc((size_t)NR * XROW);
    float* yb   = alloc((size_t)NR * DI);
    float* rmean= alloc(NR);
    float* rinv = alloc(NR);
    float* pooled = alloc((size_t)BB * DD);
    float* parts_out = alloc((size_t)4 * NR * DD);        // out-proj split-K partials
    float* parts_x   = alloc((size_t)XZSPLIT * NR * XROW); // xdbl split-K partials

    k_knn<<<BB * PP, 256, 0, stream>>>(data, knn_idx, centers);
    k_pe_mlp<<<BB * PP, 256, 0, stream>>>(data, knn_idx,
        pe_w1, pe_b1, pe_g1, pe_be1, pe_w2, pe_b2, pe_g2, pe_be2,
        pe_w3, pe_b3, pe_g3, pe_be3, tokens);
    k_sfc<<<BB, 64, 0, stream>>>(centers, order_h, order_th);
    {
        int nt = BB * LL * DD;
        k_build_t<<<(nt + 255) / 256, 256, 0, stream>>>(tokens, order_h, order_th,
            oi_h_scale, oi_h_shift, oi_th_scale, oi_th_shift, pos_embed, t);
    }

    for (int i = 0; i < DEPTH; i++) {
        const float* ln_g = blk_ln_g + i * DD;
        const float* ln_b = blk_ln_b + i * DD;
        const float* in_w = blk_in_w + (size_t)i * 2 * DI * DD;
        const float* cw   = blk_conv_w + (size_t)i * DI * DCONV;
        const float* cb   = blk_conv_b + (size_t)i * DI;
        const float* xp   = blk_xp_w + (size_t)i * XROW * DI;
        const float* dtw  = blk_dt_w + (size_t)i * DI * DTR;
        const float* dtb  = blk_dt_b + (size_t)i * DI;
        const float* Al   = blk_Alog + (size_t)i * DI * DS;
        const float* Dpp  = blk_D + (size_t)i * DI;
        const float* ow   = blk_out_w + (size_t)i * DD * DI;

        // t += residual partials (layers >= 1), LN row stats
        k_stats<<<NR / 4, 256, 0, stream>>>(t, (i == 0) ? nullptr : parts_out, rmean, rinv);
        // xz = LN(t) @ in_w^T   (1024 x 1536, K=384)
        k_gemm128<1><<<dim3(2 * DI / 128, NR / 64, 1), 256, 0, stream>>>(
            t, DD, in_w, DD, rmean, rinv, ln_g, ln_b, xz, 2 * DI, 0, DD);
        // xdbl partials = silu(conv(xz)) @ xp^T   (1024 x 56, K=768, split 12)
        k_gemm_xdbl<<<dim3(1, NR / 64, XZSPLIT), 256, 0, stream>>>(
            xz, cw, cb, xp, parts_x, DI / XZSPLIT);
        k_xred<<<(NR * XROW + 255) / 256, 256, 0, stream>>>(parts_x, xdbl);
        // chunk-parallel scan (delta dot + conv-u recompute fused)
        k_scan<<<BB * DI / 2, 256, 0, stream>>>(xdbl, xz, cw, cb, dtw, dtb, Al, Dpp, yb);
        // out-proj partials = yb @ ow^T   (1024 x 384, K=768, split 4)
        k_gemm128<0><<<dim3(DD / 128, NR / 64, 4), 256, 0, stream>>>(
            yb, DI, ow, DI, nullptr, nullptr, nullptr, nullptr,
            parts_out, DD, (size_t)NR * DD, DI / 4);
    }

    k_ln<<<NR, 64, 0, stream>>>(t, parts_out, norm_g, norm_b, xln);
    k_mean<<<(BB * DD + 255) / 256, 256, 0, stream>>>(xln, pooled);
    k_mlp<<<BB, 256, 0, stream>>>(pooled, mlp_w1, mlp_b1, mlp_w2, mlp_b2, mlp_w3, mlp_b3,
                                  (float*)d_out);
}

// Round 6
// 1178.803 us; speedup vs baseline: 3.1838x; 1.2799x over previous
//
#include <hip/hip_runtime.h>
#include <math.h>

#define BB 8
#define NN 2048
#define PP 64
#define KK 32
#define DD 384
#define DEPTH 12
#define DI 768
#define DS 16
#define DCONV 4
#define DTR 24
#define NC 40
#define LL 128  // 2*PP
#define XROW (DTR + 2 * DS)  // 56
#define NR (BB * LL)         // 1024
#define XZSPLIT 12           // split-K for xdbl gemm
#define OSPLIT 4             // split-K for out-proj gemm

using bf16x8 = __attribute__((ext_vector_type(8))) short;
using floatx4 = __attribute__((ext_vector_type(4))) float;

// ---------------------------------------------------------------- helpers
__device__ __forceinline__ float gelu_exact(float x) {
    return 0.5f * x * (1.0f + erff(x * 0.70710678118654752440f));
}
__device__ __forceinline__ float siluf(float x) {
    return x / (1.0f + expf(-x));
}
__device__ __forceinline__ unsigned short f2bf(float f) {
    unsigned u = __float_as_uint(f);
    u += 0x7fffu + ((u >> 16) & 1u);   // round-to-nearest-even
    return (unsigned short)(u >> 16);
}
__device__ __forceinline__ unsigned spread_bits(unsigned v) {
    v &= 1023u;
    v = (v | (v << 16)) & 50331903u;
    v = (v | (v << 8)) & 50393103u;
    v = (v | (v << 4)) & 51130563u;
    v = (v | (v << 2)) & 153391689u;
    return v;
}

// ---------------------------------------------------------------- fp32 -> bf16 bulk convert
__global__ void k_w2bf(const float* __restrict__ src, unsigned short* __restrict__ dst, int n)
{
    int i = (blockIdx.x * 256 + threadIdx.x) * 4;
    if (i >= n) return;
    float4 v = *(const float4*)(src + i);
    dst[i + 0] = f2bf(v.x);
    dst[i + 1] = f2bf(v.y);
    dst[i + 2] = f2bf(v.z);
    dst[i + 3] = f2bf(v.w);
}

// ---------------------------------------------------------------- KNN: one block per (b,p)
__global__ __launch_bounds__(256) void k_knn(const float* __restrict__ data,
                                             int* __restrict__ knn_out,
                                             float* __restrict__ centers)
{
    const int bp = blockIdx.x;
    const int b = bp >> 6, p = bp & 63;
    const int tid = threadIdx.x;
    const int lane = tid & 63, wid = tid >> 6;
    const float* X = data + (size_t)b * NN * 3;

    const float cx = X[p * 32 * 3 + 0];
    const float cy = X[p * 32 * 3 + 1];
    const float cz = X[p * 32 * 3 + 2];
    if (tid == 0) {
        centers[(b * PP + p) * 3 + 0] = cx;
        centers[(b * PP + p) * 3 + 1] = cy;
        centers[(b * PP + p) * 3 + 2] = cz;
    }

    unsigned long long pk[8];
#pragma unroll
    for (int q = 0; q < 8; q++) {
        int i = tid + 256 * q;
        float dx = cx - X[i * 3 + 0];
        float dy = cy - X[i * 3 + 1];
        float dz = cz - X[i * 3 + 2];
        float d2 = dx * dx + dy * dy + dz * dz;
        pk[q] = ((unsigned long long)__float_as_uint(d2) << 32) | (unsigned)i;
    }

    __shared__ unsigned long long wred[4];
    __shared__ int klist[KK];
    for (int k = 0; k < KK; k++) {
        unsigned long long m = pk[0];
#pragma unroll
        for (int q = 1; q < 8; q++) m = pk[q] < m ? pk[q] : m;
#pragma unroll
        for (int off = 32; off; off >>= 1) {
            unsigned long long o = __shfl_xor(m, off);
            m = o < m ? o : m;
        }
        if (lane == 0) wred[wid] = m;
        __syncthreads();
        unsigned long long g = wred[0];
#pragma unroll
        for (int w = 1; w < 4; w++) g = wred[w] < g ? wred[w] : g;
#pragma unroll
        for (int q = 0; q < 8; q++)
            if (pk[q] == g) pk[q] = ~0ull;
        if (tid == 0) klist[k] = (int)(g & 0xffffffffu);
        __syncthreads();
    }
    if (tid < KK) knn_out[bp * KK + tid] = klist[tid];
}

// ---------------------------------------------------------------- patch-embed MLP: one block per (b,p)
__global__ __launch_bounds__(256) void k_pe_mlp(
    const float* __restrict__ data, const int* __restrict__ knn_in,
    const float* __restrict__ w1, const float* __restrict__ b1,
    const float* __restrict__ g1, const float* __restrict__ be1,
    const float* __restrict__ w2, const float* __restrict__ b2,
    const float* __restrict__ g2, const float* __restrict__ be2,
    const float* __restrict__ w3, const float* __restrict__ b3,
    const float* __restrict__ g3, const float* __restrict__ be3,
    float* __restrict__ tokens)
{
    const int bp = blockIdx.x;
    const int b = bp >> 6, p = bp & 63;
    const int tid = threadIdx.x;
    const float* X = data + (size_t)b * NN * 3;
    const float inv_den = 0.99999500003749968752f; // 1/sqrt(1+1e-5)

    __shared__ float nxs[KK * 3];
    __shared__ float h1s[KK * 64];
    __shared__ float h2s[KK * 136];

    const float cx = X[p * 32 * 3 + 0];
    const float cy = X[p * 32 * 3 + 1];
    const float cz = X[p * 32 * 3 + 2];
    if (tid < KK) {
        int q = knn_in[bp * KK + tid];
        nxs[tid * 3 + 0] = X[q * 3 + 0] - cx;
        nxs[tid * 3 + 1] = X[q * 3 + 1] - cy;
        nxs[tid * 3 + 2] = X[q * 3 + 2] - cz;
    }
    __syncthreads();

    for (int e = tid; e < KK * 64; e += 256) {
        int j = e >> 6, c = e & 63;
        float v = nxs[j * 3 + 0] * w1[c * 3 + 0] + nxs[j * 3 + 1] * w1[c * 3 + 1] +
                  nxs[j * 3 + 2] * w1[c * 3 + 2] + b1[c];
        v = v * (g1[c] * inv_den) + be1[c];
        h1s[j * 64 + c] = gelu_exact(v);
    }
    __syncthreads();

    for (int e = tid; e < KK * 128; e += 256) {
        int j = e >> 7, c = e & 127;
        const float4* wr = (const float4*)(w2 + (size_t)c * 64);
        const float4* hr = (const float4*)(h1s + j * 64);
        float acc = 0.f;
#pragma unroll
        for (int q = 0; q < 16; q++) {
            float4 wv = wr[q], hv = hr[q];
            acc += hv.x * wv.x + hv.y * wv.y + hv.z * wv.z + hv.w * wv.w;
        }
        float v = (acc + b2[c]) * (g2[c] * inv_den) + be2[c];
        h2s[j * 136 + c] = gelu_exact(v);
    }
    __syncthreads();

    const int cg = tid >> 2;
    const int jg = tid & 3;
    const int c0 = cg * 6;
    float acc[6][8];
#pragma unroll
    for (int i = 0; i < 6; i++)
#pragma unroll
        for (int j = 0; j < 8; j++) acc[i][j] = 0.f;

    for (int q = 0; q < 32; q++) {
        float4 hv[8];
#pragma unroll
        for (int jj = 0; jj < 8; jj++)
            hv[jj] = *(const float4*)(h2s + (jg + 4 * jj) * 136 + q * 4);
#pragma unroll
        for (int ci = 0; ci < 6; ci++) {
            float4 wv = *(const float4*)(w3 + (size_t)(c0 + ci) * 128 + q * 4);
#pragma unroll
            for (int jj = 0; jj < 8; jj++) {
                acc[ci][jj] += hv[jj].x * wv.x + hv[jj].y * wv.y +
                               hv[jj].z * wv.z + hv[jj].w * wv.w;
            }
        }
    }
#pragma unroll
    for (int ci = 0; ci < 6; ci++) {
        int c = c0 + ci;
        float bi = b3[c], sc = g3[c] * inv_den, sh = be3[c];
        float m = -3.4e38f;
#pragma unroll
        for (int jj = 0; jj < 8; jj++)
            m = fmaxf(m, (acc[ci][jj] + bi) * sc + sh);
        m = fmaxf(m, __shfl_xor(m, 1, 4));
        m = fmaxf(m, __shfl_xor(m, 2, 4));
        if (jg == 0) tokens[((size_t)b * PP + p) * DD + c] = m;
    }
}

// ---------------------------------------------------------------- SFC orders
__global__ __launch_bounds__(64) void k_sfc(const float* __restrict__ centers,
                                            int* __restrict__ order_h,
                                            int* __restrict__ order_th)
{
    const int b = blockIdx.x;
    const int tid = threadIdx.x;
    float cc[3];
    cc[0] = centers[(b * PP + tid) * 3 + 0];
    cc[1] = centers[(b * PP + tid) * 3 + 1];
    cc[2] = centers[(b * PP + tid) * 3 + 2];

    __shared__ float csh[PP][3];
    __shared__ float slo[3], shi[3];
    csh[tid][0] = cc[0]; csh[tid][1] = cc[1]; csh[tid][2] = cc[2];
    __syncthreads();
    if (tid == 0) {
        for (int k = 0; k < 3; k++) {
            float lo = csh[0][k], hi = csh[0][k];
            for (int j = 1; j < PP; j++) { lo = fminf(lo, csh[j][k]); hi = fmaxf(hi, csh[j][k]); }
            slo[k] = lo; shi[k] = hi;
        }
    }
    __syncthreads();

    int q[3];
    for (int k = 0; k < 3; k++) {
        float t = (cc[k] - slo[k]) / (shi[k] - slo[k] + 1e-6f) * 1023.0f;
        int qi = (int)t;
        qi = qi < 0 ? 0 : (qi > 1023 ? 1023 : qi);
        q[k] = qi;
    }
    unsigned kh = spread_bits((unsigned)q[0]) | (spread_bits((unsigned)q[1]) << 1) |
                  (spread_bits((unsigned)q[2]) << 2);
    unsigned kt = spread_bits((unsigned)q[2]) | (spread_bits((unsigned)q[1]) << 1) |
                  (spread_bits((unsigned)q[0]) << 2);

    __shared__ unsigned khs[PP], kts[PP];
    khs[tid] = kh; kts[tid] = kt;
    __syncthreads();
    int rh = 0, rt = 0;
    for (int j = 0; j < PP; j++) {
        unsigned a = khs[j];
        rh += (a < kh) || (a == kh && j < tid);
        unsigned c = kts[j];
        rt += (c < kt) || (c == kt && j < tid);
    }
    order_h[b * PP + rh] = tid;
    order_th[b * PP + rt] = tid;
}

// ---------------------------------------------------------------- build token sequence
__global__ void k_build_t(const float* __restrict__ tokens,
                          const int* __restrict__ order_h, const int* __restrict__ order_th,
                          const float* __restrict__ hs, const float* __restrict__ hb,
                          const float* __restrict__ ts, const float* __restrict__ tb,
                          const float* __restrict__ pos, float* __restrict__ t)
{
    int idx = blockIdx.x * blockDim.x + threadIdx.x;
    if (idx >= BB * LL * DD) return;
    int d = idx % DD;
    int l = (idx / DD) % LL;
    int b = idx / (DD * LL);
    float v;
    if (l < PP) {
        int src = order_h[b * PP + l];
        v = tokens[((size_t)b * PP + src) * DD + d] * hs[d] + hb[d] + pos[l * DD + d];
    } else {
        int ll2 = l - PP;
        int src = order_th[b * PP + ll2];
        v = tokens[((size_t)b * PP + src) * DD + d] * ts[d] + tb[d] + pos[ll2 * DD + d];
    }
    t[idx] = v;
}

// ---------------------------------------------------------------- residual-accumulate + LN stats + bf16 LN output
// t += sum of OSPLIT out-proj partial slices (if parts != null), write t back,
// and emit the LayerNorm'd row directly as bf16 (A-operand of the xz MFMA GEMM).
__global__ __launch_bounds__(256) void k_stats(float* __restrict__ t,
                                               const float* __restrict__ parts,
                                               const float* __restrict__ g,
                                               const float* __restrict__ gb,
                                               unsigned short* __restrict__ tbf)
{
    const int tid = threadIdx.x;
    const int wid = tid >> 6, lane = tid & 63;
    const int row = blockIdx.x * 4 + wid;
    const size_t base = (size_t)row * DD;
    float v[6];
    float s = 0.f;
#pragma unroll
    for (int j = 0; j < 6; j++) {
        int i = lane + 64 * j;
        float x = t[base + i];
        if (parts) {
            x += parts[base + i] + parts[(size_t)NR * DD + base + i] +
                 parts[2 * (size_t)NR * DD + base + i] + parts[3 * (size_t)NR * DD + base + i];
            t[base + i] = x;
        }
        v[j] = x; s += x;
    }
#pragma unroll
    for (int off = 32; off; off >>= 1) s += __shfl_xor(s, off);
    float mean = s * (1.0f / DD);
    float vs = 0.f;
#pragma unroll
    for (int j = 0; j < 6; j++) { float dd = v[j] - mean; vs += dd * dd; }
#pragma unroll
    for (int off = 32; off; off >>= 1) vs += __shfl_xor(vs, off);
    float inv = 1.0f / sqrtf(vs * (1.0f / DD) + 1e-5f);
#pragma unroll
    for (int j = 0; j < 6; j++) {
        int i = lane + 64 * j;
        tbf[base + i] = f2bf((v[j] - mean) * inv * g[i] + gb[i]);
    }
}

// ---------------------------------------------------------------- bf16 MFMA GEMM, 128x128 tile, 4 waves
// C[M,N](fp32) = Abf[M,K] @ Wbf[N,K]^T.  Fragments loaded directly from global
// (row-major bf16 => 16B contiguous per fragment, no LDS).  Split-K via blockIdx.z
// writing to C + z*cstride.  Requires M%128==0, N%128==0, kchunk%32==0.
__global__ __launch_bounds__(256) void k_mfma_gemm(
    const unsigned short* __restrict__ Abf, int lda,
    const unsigned short* __restrict__ Wbf, int ldb,
    float* __restrict__ C, int ldc, size_t cstride, int kchunk)
{
    const int tid = threadIdx.x;
    const int wave = tid >> 6, lane = tid & 63;
    const int quad = lane >> 4, r = lane & 15;
    const int wm = wave >> 1, wn = wave & 1;
    const int m0 = blockIdx.y * 128 + wm * 64;
    const int n0 = blockIdx.x * 128 + wn * 64;
    const int kbeg = blockIdx.z * kchunk;
    float* Cz = C + (size_t)blockIdx.z * cstride;

    floatx4 acc[4][4] = {};

    const unsigned short* Ab = Abf + (size_t)(m0 + r) * lda + quad * 8 + kbeg;
    const unsigned short* Bb = Wbf + (size_t)(n0 + r) * ldb + quad * 8 + kbeg;

    for (int k0 = 0; k0 < kchunk; k0 += 32) {
        bf16x8 af[4], bf[4];
#pragma unroll
        for (int i = 0; i < 4; i++) {
            af[i] = *(const bf16x8*)(Ab + (size_t)(i * 16) * lda + k0);
            bf[i] = *(const bf16x8*)(Bb + (size_t)(i * 16) * ldb + k0);
        }
#pragma unroll
        for (int i = 0; i < 4; i++)
#pragma unroll
            for (int j = 0; j < 4; j++)
                acc[i][j] = __builtin_amdgcn_mfma_f32_16x16x32_bf16(af[i], bf[j], acc[i][j], 0, 0, 0);
    }

    // C/D layout: col = lane&15, row = quad*4 + reg   [m89/m91 verified]
#pragma unroll
    for (int i = 0; i < 4; i++)
#pragma unroll
        for (int r2 = 0; r2 < 4; r2++) {
            float* cp = Cz + (size_t)(m0 + i * 16 + quad * 4 + r2) * ldc + n0 + r;
#pragma unroll
            for (int j = 0; j < 4; j++)
                cp[j * 16] = acc[i][j][r2];
        }
}

// ---------------------------------------------------------------- xdbl GEMM with fused causal conv+SiLU
__global__ __launch_bounds__(256) void k_gemm_xdbl(
    const float* __restrict__ xz, const float* __restrict__ cw, const float* __restrict__ cb,
    const float* __restrict__ xp, float* __restrict__ parts, int kchunk)
{
    __shared__ float As[16][68];
    __shared__ float Bs[16][68];
    __shared__ float cwL[64][4];
    __shared__ float cbL[64];
    const int tid = threadIdx.x;
    const int tx = tid & 15, ty = tid >> 4;
    const int m0 = blockIdx.y * 64;
    const int z = blockIdx.z;
    const int kbeg = z * kchunk;

    if (tid < 64) {
        cbL[tid] = cb[kbeg + tid];
        *(float4*)cwL[tid] = *(const float4*)(cw + (size_t)(kbeg + tid) * 4);
    }
    __syncthreads();

    const int lm = tid >> 2;
    const int lk = (tid & 3) * 4;
    const int l = (m0 + lm) & (LL - 1);
    const float* xzrow = xz + (size_t)(m0 + lm) * (2 * DI);

    float acc[4][4] = {};

    for (int k0 = kbeg; k0 < kbeg + kchunk; k0 += 16) {
        const int ak = k0 + lk;
        const int cl = ak - kbeg;
        float4 a = make_float4(cbL[cl + 0], cbL[cl + 1], cbL[cl + 2], cbL[cl + 3]);
#pragma unroll
        for (int j = 0; j < DCONV; j++) {
            int lt = l - (DCONV - 1) + j;
            if (lt >= 0) {
                float4 xv = *(const float4*)(xzrow + (size_t)(lt - l) * (2 * DI) + ak);
                a.x += xv.x * cwL[cl + 0][j];
                a.y += xv.y * cwL[cl + 1][j];
                a.z += xv.z * cwL[cl + 2][j];
                a.w += xv.w * cwL[cl + 3][j];
            }
        }
        a.x = siluf(a.x); a.y = siluf(a.y); a.z = siluf(a.z); a.w = siluf(a.w);

        float4 bv = make_float4(0.f, 0.f, 0.f, 0.f);
        if (lm < XROW) bv = *(const float4*)(xp + (size_t)lm * DI + ak);

        As[lk + 0][lm] = a.x; As[lk + 1][lm] = a.y; As[lk + 2][lm] = a.z; As[lk + 3][lm] = a.w;
        Bs[lk + 0][lm] = bv.x; Bs[lk + 1][lm] = bv.y; Bs[lk + 2][lm] = bv.z; Bs[lk + 3][lm] = bv.w;
        __syncthreads();
#pragma unroll
        for (int kk = 0; kk < 16; kk++) {
            float4 a2 = *(const float4*)(&As[kk][ty * 4]);
            float4 b2 = *(const float4*)(&Bs[kk][tx * 4]);
            acc[0][0] += a2.x * b2.x; acc[0][1] += a2.x * b2.y; acc[0][2] += a2.x * b2.z; acc[0][3] += a2.x * b2.w;
            acc[1][0] += a2.y * b2.x; acc[1][1] += a2.y * b2.y; acc[1][2] += a2.y * b2.z; acc[1][3] += a2.y * b2.w;
            acc[2][0] += a2.z * b2.x; acc[2][1] += a2.z * b2.y; acc[2][2] += a2.z * b2.z; acc[2][3] += a2.z * b2.w;
            acc[3][0] += a2.w * b2.x; acc[3][1] += a2.w * b2.y; acc[3][2] += a2.w * b2.z; acc[3][3] += a2.w * b2.w;
        }
        __syncthreads();
    }

    const int crow = m0 + ty * 4;
    const int ccol = tx * 4;
    if (ccol < XROW) {
        float* out = parts + (size_t)z * NR * XROW;
#pragma unroll
        for (int i = 0; i < 4; i++) {
            float* cp = out + (size_t)(crow + i) * XROW + ccol;
            *(float4*)cp = make_float4(acc[i][0], acc[i][1], acc[i][2], acc[i][3]);
        }
    }
}

// ---------------------------------------------------------------- reduce xdbl partials
__global__ void k_xred(const float* __restrict__ parts, float* __restrict__ xdbl)
{
    int i = blockIdx.x * 256 + threadIdx.x;
    if (i >= NR * XROW) return;
    float s = 0.f;
#pragma unroll
    for (int z = 0; z < XZSPLIT; z++) s += parts[(size_t)z * NR * XROW + i];
    xdbl[i] = s;
}

// ---------------------------------------------------------------- chunk-parallel selective scan (y out in bf16)
__global__ __launch_bounds__(256) void k_scan(
    const float* __restrict__ xdbl, const float* __restrict__ xz,
    const float* __restrict__ cw, const float* __restrict__ cb,
    const float* __restrict__ dtw, const float* __restrict__ dtb,
    const float* __restrict__ Alog, const float* __restrict__ Dp,
    unsigned short* __restrict__ ybf)
{
    const int tid = threadIdx.x;
    const int b = blockIdx.x / (DI / 2);
    const int d0 = (blockIdx.x % (DI / 2)) * 2;

    __shared__ float da[LL][33];
    __shared__ float Bsh[LL][DS];
    __shared__ float Csh[LL][DS];
    __shared__ float dus[LL][2];
    __shared__ float us[LL][2];
    __shared__ float zs[LL][2];
    __shared__ float ApL[2][DS][9];
    __shared__ float HlL[2][DS][9];
    __shared__ float hst[2][DS][9];

    {
        const int t = tid >> 1, dl = tid & 1;
        const int d = d0 + dl;
        const size_t row = (size_t)b * LL + t;
        const float* xd = xdbl + row * XROW;
        const float* w = dtw + d * DTR;
        float acc = dtb[d];
#pragma unroll
        for (int k = 0; k < DTR; k++) acc += xd[k] * w[k];
        float delta = fmaxf(acc, 0.f) + log1pf(__expf(-fabsf(acc)));  // softplus
        float u = cb[d];
#pragma unroll
        for (int j = 0; j < DCONV; j++) {
            int lt = t - (DCONV - 1) + j;
            if (lt >= 0) u += xz[((size_t)b * LL + lt) * (2 * DI) + d] * cw[d * DCONV + j];
        }
        u = siluf(u);
        dus[t][dl] = delta * u;
        us[t][dl] = u;
        zs[t][dl] = siluf(xz[row * (2 * DI) + DI + d]);
#pragma unroll
        for (int s = 0; s < DS; s++)
            da[t][2 * s + dl] = __expf(delta * (-__expf(Alog[d * DS + s])));
    }
    for (int i = tid; i < LL * DS; i += 256) {
        int t = i >> 4, s = i & 15;
        const float* xd = xdbl + ((size_t)b * LL + t) * XROW;
        Bsh[t][s] = xd[DTR + s];
        Csh[t][s] = xd[DTR + DS + s];
    }
    __syncthreads();

    const int s = tid & 15;
    const int dl = (tid >> 4) & 1;
    const int c = tid >> 5;

    {
        float h = 0.f, Ap = 1.f;
#pragma unroll
        for (int q = 0; q < 16; q++) {
            int t = c * 16 + q;
            float a = da[t][2 * s + dl];
            h = h * a + dus[t][dl] * Bsh[t][s];
            Ap *= a;
        }
        ApL[dl][s][c] = Ap;
        HlL[dl][s][c] = h;
    }
    __syncthreads();
    if (tid < 32) {
        int s2 = tid & 15, d2 = tid >> 4;
        float hs = 0.f;
#pragma unroll
        for (int cc = 0; cc < 8; cc++) {
            hst[d2][s2][cc] = hs;
            hs = ApL[d2][s2][cc] * hs + HlL[d2][s2][cc];
        }
    }
    __syncthreads();

    {
        const float Dd = Dp[d0 + dl];
        float h = hst[dl][s][c];
        unsigned short* yc = ybf + ((size_t)b * LL + c * 16) * DI + (d0 + dl);
#pragma unroll
        for (int q = 0; q < 16; q++) {
            int t = c * 16 + q;
            float a = da[t][2 * s + dl];
            h = h * a + dus[t][dl] * Bsh[t][s];
            float p = h * Csh[t][s];
            p += __shfl_xor(p, 1, 16);
            p += __shfl_xor(p, 2, 16);
            p += __shfl_xor(p, 4, 16);
            p += __shfl_xor(p, 8, 16);
            if (s == 0) yc[(size_t)q * DI] = f2bf((p + Dd * us[t][dl]) * zs[t][dl]);
        }
    }
}

// ---------------------------------------------------------------- final layernorm (wave per row) + residual partials
__global__ __launch_bounds__(64) void k_ln(const float* __restrict__ x,
                                           const float* __restrict__ parts,
                                           const float* __restrict__ g,
                                           const float* __restrict__ bb,
                                           float* __restrict__ y)
{
    const int row = blockIdx.x;
    const int tid = threadIdx.x;
    const size_t base = (size_t)row * DD;
    float v[6];
    float s = 0.f;
#pragma unroll
    for (int j = 0; j < 6; j++) {
        int i = tid + 64 * j;
        float xv = x[base + i] + parts[base + i] + parts[(size_t)NR * DD + base + i] +
                   parts[2 * (size_t)NR * DD + base + i] + parts[3 * (size_t)NR * DD + base + i];
        v[j] = xv; s += xv;
    }
#pragma unroll
    for (int off = 32; off; off >>= 1) s += __shfl_xor(s, off);
    float mean = s * (1.0f / DD);
    float vs = 0.f;
#pragma unroll
    for (int j = 0; j < 6; j++) { float dd = v[j] - mean; vs += dd * dd; }
#pragma unroll
    for (int off = 32; off; off >>= 1) vs += __shfl_xor(vs, off);
    float inv = 1.0f / sqrtf(vs * (1.0f / DD) + 1e-5f);
#pragma unroll
    for (int j = 0; j < 6; j++) {
        int i = tid + 64 * j;
        y[base + i] = (v[j] - mean) * inv * g[i] + bb[i];
    }
}

// ---------------------------------------------------------------- mean over L
__global__ void k_mean(const float* __restrict__ xln, float* __restrict__ pooled)
{
    int idx = blockIdx.x * blockDim.x + threadIdx.x;
    if (idx >= BB * DD) return;
    int b = idx / DD, d = idx % DD;
    float sv = 0.f;
    for (int l = 0; l < LL; l++) sv += xln[((size_t)b * LL + l) * DD + d];
    pooled[idx] = sv / (float)LL;
}

// ---------------------------------------------------------------- head MLP (one block per batch)
__global__ __launch_bounds__(256) void k_mlp(const float* __restrict__ pooled,
    const float* __restrict__ w1, const float* __restrict__ b1,
    const float* __restrict__ w2, const float* __restrict__ b2,
    const float* __restrict__ w3, const float* __restrict__ b3,
    float* __restrict__ out)
{
    int b = blockIdx.x, tid = threadIdx.x;
    __shared__ float pl[DD];
    __shared__ float h1[256];
    __shared__ float h2[64];
    for (int i = tid; i < DD; i += 256) pl[i] = pooled[b * DD + i];
    __syncthreads();
    {
        float acc = b1[tid];
        const float* wr = w1 + (size_t)tid * DD;
        for (int k = 0; k < DD; k++) acc += pl[k] * wr[k];
        h1[tid] = fmaxf(acc, 0.f);
    }
    __syncthreads();
    if (tid < 64) {
        float acc = b2[tid];
        const float* wr = w2 + (size_t)tid * 256;
        for (int k = 0; k < 256; k++) acc += h1[k] * wr[k];
        h2[tid] = fmaxf(acc, 0.f);
    }
    __syncthreads();
    if (tid < NC) {
        float acc = b3[tid];
        const float* wr = w3 + (size_t)tid * 64;
        for (int k = 0; k < 64; k++) acc += h2[k] * wr[k];
        out[b * NC + tid] = acc;
    }
}

// ---------------------------------------------------------------- launch
extern "C" void kernel_launch(void* const* d_in, const int* in_sizes, int n_in,
                              void* d_out, int out_size, void* d_ws, size_t ws_size,
                              hipStream_t stream)
{
    const float* data      = (const float*)d_in[0];
    const float* pe_w1     = (const float*)d_in[1];
    const float* pe_b1     = (const float*)d_in[2];
    const float* pe_g1     = (const float*)d_in[3];
    const float* pe_be1    = (const float*)d_in[4];
    const float* pe_w2     = (const float*)d_in[5];
    const float* pe_b2     = (const float*)d_in[6];
    const float* pe_g2     = (const float*)d_in[7];
    const float* pe_be2    = (const float*)d_in[8];
    const float* pe_w3     = (const float*)d_in[9];
    const float* pe_b3     = (const float*)d_in[10];
    const float* pe_g3     = (const float*)d_in[11];
    const float* pe_be3    = (const float*)d_in[12];
    const float* oi_h_scale  = (const float*)d_in[13];
    const float* oi_h_shift  = (const float*)d_in[14];
    const float* oi_th_scale = (const float*)d_in[15];
    const float* oi_th_shift = (const float*)d_in[16];
    const float* pos_embed = (const float*)d_in[17];
    const float* blk_ln_g  = (const float*)d_in[18];
    const float* blk_ln_b  = (const float*)d_in[19];
    const float* blk_in_w  = (const float*)d_in[20];
    const float* blk_conv_w = (const float*)d_in[21];
    const float* blk_conv_b = (const float*)d_in[22];
    const float* blk_xp_w  = (const float*)d_in[23];
    const float* blk_dt_w  = (const float*)d_in[24];
    const float* blk_dt_b  = (const float*)d_in[25];
    const float* blk_Alog  = (const float*)d_in[26];
    const float* blk_D     = (const float*)d_in[27];
    const float* blk_out_w = (const float*)d_in[28];
    const float* norm_g    = (const float*)d_in[29];
    const float* norm_b    = (const float*)d_in[30];
    const float* mlp_w1    = (const float*)d_in[31];
    const float* mlp_b1    = (const float*)d_in[32];
    const float* mlp_w2    = (const float*)d_in[33];
    const float* mlp_b2    = (const float*)d_in[34];
    const float* mlp_w3    = (const float*)d_in[35];
    const float* mlp_b3    = (const float*)d_in[36];

    float* ws = (float*)d_ws;
    size_t off = 0;
    auto alloc = [&](size_t n) { float* p = ws + off; off += (n + 63) & ~(size_t)63; return p; };
    float* tokens  = alloc((size_t)BB * PP * DD);
    float* centers = alloc((size_t)BB * PP * 3);
    int*   order_h = (int*)alloc((size_t)BB * PP);
    int*   order_th= (int*)alloc((size_t)BB * PP);
    int*   knn_idx = (int*)alloc((size_t)BB * PP * KK);
    float* t    = alloc((size_t)NR * DD);
    float* xln  = alloc((size_t)NR * DD);
    float* xz   = alloc((size_t)NR * 2 * DI);
    float* xdbl = alloc((size_t)NR * XROW);
    float* pooled = alloc((size_t)BB * DD);
    float* parts_out = alloc((size_t)OSPLIT * NR * DD);      // out-proj split-K partials
    float* parts_x   = alloc((size_t)XZSPLIT * NR * XROW);   // xdbl split-K partials
    unsigned short* tbf   = (unsigned short*)alloc((size_t)NR * DD / 2);          // LN(t) bf16
    unsigned short* ybf   = (unsigned short*)alloc((size_t)NR * DI / 2);          // scan out bf16
    unsigned short* inwbf = (unsigned short*)alloc((size_t)DEPTH * 2 * DI * DD / 2);
    unsigned short* owbf  = (unsigned short*)alloc((size_t)DEPTH * DD * DI / 2);

    // one-shot weight conversion to bf16
    {
        int n1 = DEPTH * 2 * DI * DD;   // 7,077,888
        int n2 = DEPTH * DD * DI;       // 3,538,944
        k_w2bf<<<(n1 / 4 + 255) / 256, 256, 0, stream>>>(blk_in_w, inwbf, n1);
        k_w2bf<<<(n2 / 4 + 255) / 256, 256, 0, stream>>>(blk_out_w, owbf, n2);
    }

    k_knn<<<BB * PP, 256, 0, stream>>>(data, knn_idx, centers);
    k_pe_mlp<<<BB * PP, 256, 0, stream>>>(data, knn_idx,
        pe_w1, pe_b1, pe_g1, pe_be1, pe_w2, pe_b2, pe_g2, pe_be2,
        pe_w3, pe_b3, pe_g3, pe_be3, tokens);
    k_sfc<<<BB, 64, 0, stream>>>(centers, order_h, order_th);
    {
        int nt = BB * LL * DD;
        k_build_t<<<(nt + 255) / 256, 256, 0, stream>>>(tokens, order_h, order_th,
            oi_h_scale, oi_h_shift, oi_th_scale, oi_th_shift, pos_embed, t);
    }

    for (int i = 0; i < DEPTH; i++) {
        const float* ln_g = blk_ln_g + i * DD;
        const float* ln_b = blk_ln_b + i * DD;
        const float* cw   = blk_conv_w + (size_t)i * DI * DCONV;
        const float* cb   = blk_conv_b + (size_t)i * DI;
        const float* xp   = blk_xp_w + (size_t)i * XROW * DI;
        const float* dtw  = blk_dt_w + (size_t)i * DI * DTR;
        const float* dtb  = blk_dt_b + (size_t)i * DI;
        const float* Al   = blk_Alog + (size_t)i * DI * DS;
        const float* Dpp  = blk_D + (size_t)i * DI;
        const unsigned short* inw = inwbf + (size_t)i * 2 * DI * DD;
        const unsigned short* ow  = owbf + (size_t)i * DD * DI;

        // t += residual partials (layers >= 1), LN stats, bf16 LN output
        k_stats<<<NR / 4, 256, 0, stream>>>(t, (i == 0) ? nullptr : parts_out, ln_g, ln_b, tbf);
        // xz = LN(t) @ in_w^T   (1024 x 1536, K=384) -- bf16 MFMA
        k_mfma_gemm<<<dim3(2 * DI / 128, NR / 128, 1), 256, 0, stream>>>(
            tbf, DD, inw, DD, xz, 2 * DI, 0, DD);
        // xdbl partials = silu(conv(xz)) @ xp^T   (1024 x 56, K=768, split 12)
        k_gemm_xdbl<<<dim3(1, NR / 64, XZSPLIT), 256, 0, stream>>>(
            xz, cw, cb, xp, parts_x, DI / XZSPLIT);
        k_xred<<<(NR * XROW + 255) / 256, 256, 0, stream>>>(parts_x, xdbl);
        // chunk-parallel scan -> ybf (bf16)
        k_scan<<<BB * DI / 2, 256, 0, stream>>>(xdbl, xz, cw, cb, dtw, dtb, Al, Dpp, ybf);
        // out-proj partials = yb @ ow^T   (1024 x 384, K=768, split 4) -- bf16 MFMA
        k_mfma_gemm<<<dim3(DD / 128, NR / 128, OSPLIT), 256, 0, stream>>>(
            ybf, DI, ow, DI, parts_out, DD, (size_t)NR * DD, DI / OSPLIT);
    }

    k_ln<<<NR, 64, 0, stream>>>(t, parts_out, norm_g, norm_b, xln);
    k_mean<<<(BB * DD + 255) / 256, 256, 0, stream>>>(xln, pooled);
    k_mlp<<<BB, 256, 0, stream>>>(pooled, mlp_w1, mlp_b1, mlp_w2, mlp_b2, mlp_w3, mlp_b3,
                                  (float*)d_out);
}